// Round 2
// baseline (619.101 us; speedup 1.0000x reference)
//
#include <hip/hip_runtime.h>
#include <hip/hip_bf16.h>
#include <stdint.h>

typedef unsigned short u16;
typedef __attribute__((ext_vector_type(8))) short s16x8;   // 8 bf16 (4 VGPRs) — MFMA A/B frag
typedef __attribute__((ext_vector_type(4))) float f32x4;   // MFMA C/D frag

#define B_   2
#define T_   2048
#define D_   1024
#define H_   16
#define HD_  64
#define DFF_ 4096
#define M_   (B_*T_)   // 4096

// ---------- helpers ----------
__device__ __forceinline__ u16 f2b(float f){          // fp32 -> bf16, RNE
  uint32_t u = __float_as_uint(f);
  u += 0x7FFFu + ((u >> 16) & 1u);
  return (u16)(u >> 16);
}
__device__ __forceinline__ float b2f(u16 u){ return __uint_as_float(((uint32_t)u) << 16); }

// async global->LDS, 16B per lane. LDS dest is wave-uniform-base + lane*16 (lane-linear).
__device__ __forceinline__ void gl_lds16(const void* g, void* l){
  __builtin_amdgcn_global_load_lds((const __attribute__((address_space(1))) void*)g,
                                   (__attribute__((address_space(3))) void*)l, 16, 0, 0);
}

// ---------- weight fp32 [K][N] -> bf16 transposed [N][K] ----------
__global__ __launch_bounds__(256) void wconv(const float* __restrict__ W, u16* __restrict__ Wt,
                                             int K, int N){
  const int k0 = blockIdx.x << 6, n0 = blockIdx.y << 6;
  __shared__ u16 tile[64][68];                 // +4 pad breaks bank conflicts on transpose read
  const int tid = threadIdx.x;
  const int rr = tid >> 4, c4 = (tid & 15) << 2;
  #pragma unroll
  for (int rep = 0; rep < 4; rep++){
    int r = rr + (rep << 4);
    float4 v = *reinterpret_cast<const float4*>(W + (size_t)(k0 + r)*N + n0 + c4);
    tile[r][c4+0] = f2b(v.x); tile[r][c4+1] = f2b(v.y);
    tile[r][c4+2] = f2b(v.z); tile[r][c4+3] = f2b(v.w);
  }
  __syncthreads();
  const int rn = tid >> 2, kb = (tid & 3) << 4;
  u16 tmp[16];
  #pragma unroll
  for (int j = 0; j < 16; j++) tmp[j] = tile[kb + j][rn];
  ushort4* dst = reinterpret_cast<ushort4*>(Wt + (size_t)(n0 + rn)*K + k0 + kb);
  dst[0] = make_ushort4(tmp[0], tmp[1], tmp[2], tmp[3]);
  dst[1] = make_ushort4(tmp[4], tmp[5], tmp[6], tmp[7]);
  dst[2] = make_ushort4(tmp[8], tmp[9], tmp[10], tmp[11]);
  dst[3] = make_ushort4(tmp[12], tmp[13], tmp[14], tmp[15]);
}

// ---------- LayerNorm: fp32 [rows][1024] -> bf16 ----------
__global__ __launch_bounds__(256) void ln_kernel(const float* __restrict__ X,
                                                 const float* __restrict__ sc,
                                                 const float* __restrict__ sh,
                                                 u16* __restrict__ out){
  const int row = blockIdx.x;
  const int tid = threadIdx.x;
  const float* xr = X + ((size_t)row << 10);
  float4 a = reinterpret_cast<const float4*>(xr)[tid];
  float s = a.x + a.y + a.z + a.w;
  float q = a.x*a.x + a.y*a.y + a.z*a.z + a.w*a.w;
  #pragma unroll
  for (int o = 32; o > 0; o >>= 1){ s += __shfl_xor(s, o); q += __shfl_xor(q, o); }
  __shared__ float red[8];
  const int w = tid >> 6;
  if ((tid & 63) == 0){ red[w] = s; red[4 + w] = q; }
  __syncthreads();
  float S = red[0] + red[1] + red[2] + red[3];
  float Q = red[4] + red[5] + red[6] + red[7];
  float mean = S * (1.0f/1024.0f);
  float var  = Q * (1.0f/1024.0f) - mean*mean;   // population var (ddof=0)
  float inv = rsqrtf(var + 1e-5f);
  float4 gsc = reinterpret_cast<const float4*>(sc)[tid];
  float4 gsh = reinterpret_cast<const float4*>(sh)[tid];
  ushort4 o4;
  o4.x = f2b((a.x - mean)*inv*gsc.x + gsh.x);
  o4.y = f2b((a.y - mean)*inv*gsc.y + gsh.y);
  o4.z = f2b((a.z - mean)*inv*gsc.z + gsh.z);
  o4.w = f2b((a.w - mean)*inv*gsc.w + gsh.w);
  reinterpret_cast<ushort4*>(out + ((size_t)row << 10))[tid] = o4;
}

// ---------- bf16 GEMM: C[M,N] = A[M,K] @ Bt[N,K]^T, 128x128 tile, BK=32 ----------
template<int EPI>
__global__ __launch_bounds__(256) void gemm_k(const u16* __restrict__ A, const u16* __restrict__ Bt,
                                              const float* __restrict__ bias,
                                              const float* __restrict__ resid,
                                              void* __restrict__ Cv, int M, int N, int K){
  __shared__ __align__(16) u16 As[128*32];
  __shared__ __align__(16) u16 Bs[128*32];
  const int tid = threadIdx.x;
  const int lane = tid & 63;
  const int w = tid >> 6;
  const int wr = w >> 1, wc = w & 1;           // 2x2 waves, each owns 64x64
  const int g = lane >> 4, l15 = lane & 15;
  const int tn0 = blockIdx.x << 7;
  const int tm0 = blockIdx.y << 7;

  f32x4 acc[4][4];
  #pragma unroll
  for (int i = 0; i < 4; i++)
    #pragma unroll
    for (int j = 0; j < 4; j++) acc[i][j] = (f32x4){0.f,0.f,0.f,0.f};

  const int ch0 = tid, ch1 = 256 + tid;
  const int r0 = ch0 >> 2, c0 = (((ch0 & 3) ^ ((r0 >> 1) & 3)) << 3);
  const int r1 = ch1 >> 2, c1 = (((ch1 & 3) ^ ((r1 >> 1) & 3)) << 3);
  const u16* A0 = A  + (size_t)(tm0 + r0)*K + c0;
  const u16* A1 = A  + (size_t)(tm0 + r1)*K + c1;
  const u16* B0 = Bt + (size_t)(tn0 + r0)*K + c0;
  const u16* B1 = Bt + (size_t)(tn0 + r1)*K + c1;
  u16* lA0 = As + ch0*8; u16* lA1 = As + ch1*8;
  u16* lB0 = Bs + ch0*8; u16* lB1 = Bs + ch1*8;

  for (int kt = 0; kt < K; kt += 32){
    gl_lds16(A0 + kt, lA0);
    gl_lds16(A1 + kt, lA1);
    gl_lds16(B0 + kt, lB0);
    gl_lds16(B1 + kt, lB1);
    __syncthreads();
    s16x8 af[4], bf[4];
    #pragma unroll
    for (int i = 0; i < 4; i++){
      int ra = (wr << 6) + (i << 4) + l15;
      af[i] = *reinterpret_cast<const s16x8*>(As + ra*32 + ((g ^ ((ra >> 1) & 3)) << 3));
    }
    #pragma unroll
    for (int j = 0; j < 4; j++){
      int rb = (wc << 6) + (j << 4) + l15;
      bf[j] = *reinterpret_cast<const s16x8*>(Bs + rb*32 + ((g ^ ((rb >> 1) & 3)) << 3));
    }
    #pragma unroll
    for (int i = 0; i < 4; i++)
      #pragma unroll
      for (int j = 0; j < 4; j++)
        acc[i][j] = __builtin_amdgcn_mfma_f32_16x16x32_bf16(af[i], bf[j], acc[i][j], 0, 0, 0);
    __syncthreads();
  }

  #pragma unroll
  for (int i = 0; i < 4; i++){
    const int mb = tm0 + (wr << 6) + (i << 4) + (g << 2);
    #pragma unroll
    for (int j = 0; j < 4; j++){
      const int n = tn0 + (wc << 6) + (j << 4) + l15;
      #pragma unroll
      for (int rr = 0; rr < 4; rr++){
        const int m = mb + rr;
        float v = acc[i][j][rr];
        if constexpr (EPI == 1){
          const int sel = n >> 10, nn = n & 1023;
          const int hh = nn >> 6, d = nn & 63;
          ((u16*)Cv)[(size_t)sel*((size_t)M_*D_) +
                     ((((size_t)(m >> 11)*H_ + hh)*T_ + (m & 2047)) << 6) + d] = f2b(v);
        } else if constexpr (EPI == 2){
          ((float*)Cv)[(size_t)m*N + n] = v + bias[n] + resid[(size_t)m*N + n];
        } else {
          float u = v + bias[n];
          float t2 = 0.7978845608f*(u + 0.044715f*u*u*u);
          float e = __expf(2.0f*t2);
          float th = 1.0f - 2.0f/(e + 1.0f);
          ((u16*)Cv)[(size_t)m*N + n] = f2b(0.5f*u*(1.0f + th));
        }
      }
    }
  }
}

// ---------- causal flash attention, v2 ----------
// grid (pair=16, bh=32). Block p does q-tiles {p, 31-p} sequentially: 33 k-tiles each —
// perfect balance; 512 uniform blocks, 48KB LDS -> 3 blocks/CU cap -> all co-resident.
// Double-buffered K/V with in-iteration prefetch; ONE barrier per k-tile.
// exp2-domain softmax; conflict-fixed Vt/P writes (lane-rotated orders).
__global__ __launch_bounds__(256) void attn_k(const u16* __restrict__ Qg, const u16* __restrict__ Kg,
                                              const u16* __restrict__ Vg, u16* __restrict__ ctx){
  const int pr_ = blockIdx.x;
  const int bh  = blockIdx.y;
  const int tid = threadIdx.x;
  const int lane = tid & 63;
  const int w = tid >> 6;
  const int g = lane >> 4, l15 = lane & 15;

  __shared__ __align__(16) u16 Qs[64*64];
  __shared__ __align__(16) u16 Ks[2][64*64];
  __shared__ __align__(16) u16 Vt[2][64*64];     // V transposed: [d][kr], 8-slot XOR swizzle
  __shared__ __align__(16) u16 Pl[4][16*64];     // per-wave P tile

  const size_t hb = (size_t)bh * ((size_t)T_*HD_);
  const u16* Qh = Qg + hb;
  const u16* Kh = Kg + hb;
  const u16* Vh = Vg + hb;
  const int b = bh >> 4, hh = bh & 15;

  const int s_r0 = tid >> 3,        s_c0 = (((tid & 7) ^ (s_r0 & 7)) << 3);
  const int s_r1 = (256+tid) >> 3,  s_c1 = ((((256+tid) & 7) ^ (s_r1 & 7)) << 3);
  const int v_kr = tid >> 2, v_d0 = (tid & 3) << 4, v_rot = lane & 7;

  const float SC2 = 0.18033688f;                 // (1/8) * log2(e)

  for (int ph = 0; ph < 2; ++ph){
    const int qt = ph ? (31 - pr_) : pr_;
    __syncthreads();                             // protect all LDS from previous phase readers

    // stage Q + K tile0 (async), V tile0 (reg path, written immediately)
    gl_lds16(Qh + (size_t)(qt*64 + s_r0)*HD_ + s_c0, Qs + tid*8);
    gl_lds16(Qh + (size_t)(qt*64 + s_r1)*HD_ + s_c1, Qs + (256+tid)*8);
    gl_lds16(Kh + (size_t)(s_r0)*HD_ + s_c0, Ks[0] + tid*8);
    gl_lds16(Kh + (size_t)(s_r1)*HD_ + s_c1, Ks[0] + (256+tid)*8);
    {
      const u16* vs = Vh + (size_t)v_kr*HD_ + v_d0;
      ushort4 a0 = *(const ushort4*)(vs + 0);
      ushort4 a1 = *(const ushort4*)(vs + 4);
      ushort4 a2 = *(const ushort4*)(vs + 8);
      ushort4 a3 = *(const ushort4*)(vs + 12);
      u16 vals[16] = {a0.x,a0.y,a0.z,a0.w, a1.x,a1.y,a1.z,a1.w,
                      a2.x,a2.y,a2.z,a2.w, a3.x,a3.y,a3.z,a3.w};
      #pragma unroll
      for (int j = 0; j < 16; j++){
        int jj = (j + v_rot) & 15;               // rotate write order -> spread d&7 across lanes
        int d = v_d0 + jj;
        Vt[0][d*64 + ((((v_kr >> 3) ^ (d & 7))) << 3) + (v_kr & 7)] = vals[jj];
      }
    }

    f32x4 accO[4];
    #pragma unroll
    for (int j = 0; j < 4; j++) accO[j] = (f32x4){0.f,0.f,0.f,0.f};
    float mrow[4] = {-1e30f,-1e30f,-1e30f,-1e30f};
    float lrow[4] = {0.f,0.f,0.f,0.f};
    s16x8 qa[2];

    for (int kt = 0; kt <= qt; ++kt){
      const int cur = kt & 1, nxt = cur ^ 1;
      __syncthreads();                           // drains prefetch (vmcnt+lgkm); prev readers done

      if (kt == 0){                              // Q-frag hoist (Qs ready after first barrier)
        #pragma unroll
        for (int kk = 0; kk < 2; kk++){
          int ra = (w << 4) + l15;
          int slot = (kk << 2) + g;
          qa[kk] = *reinterpret_cast<const s16x8*>(Qs + ra*64 + ((slot ^ (ra & 7)) << 3));
        }
      }

      // ---- prefetch tile kt+1: K async->LDS[nxt]; V global->reg now, LDS write sunk late
      ushort4 p0, p1, p2, p3;
      const bool pf = (kt < qt);
      if (pf){
        gl_lds16(Kh + (size_t)((kt+1)*64 + s_r0)*HD_ + s_c0, Ks[nxt] + tid*8);
        gl_lds16(Kh + (size_t)((kt+1)*64 + s_r1)*HD_ + s_c1, Ks[nxt] + (256+tid)*8);
        const u16* vs = Vh + (size_t)((kt+1)*64 + v_kr)*HD_ + v_d0;
        p0 = *(const ushort4*)(vs + 0);
        p1 = *(const ushort4*)(vs + 4);
        p2 = *(const ushort4*)(vs + 8);
        p3 = *(const ushort4*)(vs + 12);
      }

      // ---- S = Q K^T from Ks[cur]
      f32x4 accS[4];
      #pragma unroll
      for (int j = 0; j < 4; j++) accS[j] = (f32x4){0.f,0.f,0.f,0.f};
      #pragma unroll
      for (int jn = 0; jn < 4; jn++){
        #pragma unroll
        for (int kk = 0; kk < 2; kk++){
          int rb = (jn << 4) + l15;
          int slot = (kk << 2) + g;
          s16x8 kf = *reinterpret_cast<const s16x8*>(Ks[cur] + rb*64 + ((slot ^ (rb & 7)) << 3));
          accS[jn] = __builtin_amdgcn_mfma_f32_16x16x32_bf16(qa[kk], kf, accS[jn], 0, 0, 0);
        }
      }

      // ---- scale to log2 domain + causal mask (diagonal tile only)
      float sv[4][4];
      #pragma unroll
      for (int jn = 0; jn < 4; jn++)
        #pragma unroll
        for (int rr = 0; rr < 4; rr++){
          float xv = accS[jn][rr] * SC2;
          if (kt == qt){
            int qrow = (w << 4) + (g << 2) + rr;
            int kcol = (jn << 4) + l15;
            if (kcol > qrow) xv = -1e30f;
          }
          sv[jn][rr] = xv;
        }

      // ---- online softmax (exp2 domain); row r = 4g+rr lives in lanes [16g..16g+15]
      float sf[4];
      #pragma unroll
      for (int rr = 0; rr < 4; rr++){
        float t = fmaxf(fmaxf(sv[0][rr], sv[1][rr]), fmaxf(sv[2][rr], sv[3][rr]));
        t = fmaxf(t, __shfl_xor(t, 1));
        t = fmaxf(t, __shfl_xor(t, 2));
        t = fmaxf(t, __shfl_xor(t, 4));
        t = fmaxf(t, __shfl_xor(t, 8));
        float mn = fmaxf(mrow[rr], t);
        sf[rr] = exp2f(mrow[rr] - mn);
        mrow[rr] = mn;
      }
      float tsum[4] = {0.f,0.f,0.f,0.f};
      const int jrot = g >> 1;                   // rotate jn order -> spread P-write banks
      #pragma unroll
      for (int j = 0; j < 4; j++){
        int jn = j ^ jrot;
        #pragma unroll
        for (int rr = 0; rr < 4; rr++){
          float pv = exp2f(sv[jn][rr] - mrow[rr]);
          tsum[rr] += pv;
          int prow = (g << 2) + rr;
          int pcol = (jn << 4) + l15;
          Pl[w][prow*64 + (((pcol >> 3) ^ (prow & 7)) << 3) + (pcol & 7)] = f2b(pv);
        }
      }
      #pragma unroll
      for (int rr = 0; rr < 4; rr++){
        float t = tsum[rr];
        t += __shfl_xor(t, 1);
        t += __shfl_xor(t, 2);
        t += __shfl_xor(t, 4);
        t += __shfl_xor(t, 8);
        lrow[rr] = lrow[rr]*sf[rr] + t;
        #pragma unroll
        for (int jn = 0; jn < 4; jn++) accO[jn][rr] *= sf[rr];
      }
      // P is per-wave: same-wave LDS write->read ordered by lgkmcnt, no barrier needed.

      // ---- O += P V from Vt[cur]
      #pragma unroll
      for (int kk = 0; kk < 2; kk++){
        int slot = (kk << 2) + g;
        s16x8 pa = *reinterpret_cast<const s16x8*>(&Pl[w][l15*64 + ((slot ^ (l15 & 7)) << 3)]);
        #pragma unroll
        for (int jn = 0; jn < 4; jn++){
          int vd = (jn << 4) + l15;
          s16x8 vbf = *reinterpret_cast<const s16x8*>(Vt[cur] + vd*64 + ((slot ^ (vd & 7)) << 3));
          accO[jn] = __builtin_amdgcn_mfma_f32_16x16x32_bf16(pa, vbf, accO[jn], 0, 0, 0);
        }
      }

      // ---- sink prefetched V into Vt[nxt] (readers of nxt finished before this iter's barrier)
      if (pf){
        u16 vals[16] = {p0.x,p0.y,p0.z,p0.w, p1.x,p1.y,p1.z,p1.w,
                        p2.x,p2.y,p2.z,p2.w, p3.x,p3.y,p3.z,p3.w};
        #pragma unroll
        for (int j = 0; j < 16; j++){
          int jj = (j + v_rot) & 15;
          int d = v_d0 + jj;
          Vt[nxt][d*64 + ((((v_kr >> 3) ^ (d & 7))) << 3) + (v_kr & 7)] = vals[jj];
        }
      }
    }

    // ---- epilogue: O/l -> ctx[(b*T+q)*D + h*64 + d]
    #pragma unroll
    for (int rr = 0; rr < 4; rr++){
      float inv = 1.0f / lrow[rr];
      int qrow = qt*64 + (w << 4) + (g << 2) + rr;
      size_t rowbase = ((size_t)(b*T_ + qrow) << 10) + ((size_t)hh << 6);
      #pragma unroll
      for (int jn = 0; jn < 4; jn++){
        int d = (jn << 4) + l15;
        ctx[rowbase + d] = f2b(accO[jn][rr] * inv);
      }
    }
  }
}

// ---------- launch ----------
extern "C" void kernel_launch(void* const* d_in, const int* in_sizes, int n_in,
                              void* d_out, int out_size, void* d_ws, size_t ws_size,
                              hipStream_t stream){
  (void)in_sizes; (void)n_in; (void)out_size; (void)ws_size;
  const float* x    = (const float*)d_in[0];
  const float* wq   = (const float*)d_in[1];
  const float* wk   = (const float*)d_in[2];
  const float* wv   = (const float*)d_in[3];
  const float* wo   = (const float*)d_in[4];
  const float* bo   = (const float*)d_in[5];
  const float* ln1s = (const float*)d_in[6];
  const float* ln1b = (const float*)d_in[7];
  const float* ln2s = (const float*)d_in[8];
  const float* ln2b = (const float*)d_in[9];
  const float* w1   = (const float*)d_in[10];
  const float* b1   = (const float*)d_in[11];
  const float* w2   = (const float*)d_in[12];
  const float* b2   = (const float*)d_in[13];
  float* out = (float*)d_out;

  char* p = (char*)d_ws;
  u16*  wqkvT = (u16*)p;  p += (size_t)3*D_*D_*2;
  u16*  woT   = (u16*)p;  p += (size_t)D_*D_*2;
  u16*  w1T   = (u16*)p;  p += (size_t)D_*DFF_*2;
  u16*  w2T   = (u16*)p;  p += (size_t)DFF_*D_*2;
  u16*  h     = (u16*)p;  p += (size_t)M_*D_*2;
  u16*  qb    = (u16*)p;  p += (size_t)M_*D_*2;
  u16*  kb    = (u16*)p;  p += (size_t)M_*D_*2;
  u16*  vb    = (u16*)p;  p += (size_t)M_*D_*2;
  u16*  ctx   = (u16*)p;  p += (size_t)M_*D_*2;
  float* x1   = (float*)p; p += (size_t)M_*D_*4;
  u16*  h2    = (u16*)p;  p += (size_t)M_*D_*2;
  u16*  ff1   = (u16*)p;  p += (size_t)M_*DFF_*2;
  (void)kb; (void)vb;

  dim3 blk(256);
  wconv<<<dim3(16,16), blk, 0, stream>>>(wq, wqkvT + 0*(size_t)D_*D_, D_, D_);
  wconv<<<dim3(16,16), blk, 0, stream>>>(wk, wqkvT + 1*(size_t)D_*D_, D_, D_);
  wconv<<<dim3(16,16), blk, 0, stream>>>(wv, wqkvT + 2*(size_t)D_*D_, D_, D_);
  wconv<<<dim3(16,16), blk, 0, stream>>>(wo, woT, D_, D_);
  wconv<<<dim3(16,64), blk, 0, stream>>>(w1, w1T, D_, DFF_);
  wconv<<<dim3(64,16), blk, 0, stream>>>(w2, w2T, DFF_, D_);

  ln_kernel<<<M_, blk, 0, stream>>>(x, ln1s, ln1b, h);
  gemm_k<1><<<dim3(24,32), blk, 0, stream>>>(h, wqkvT, nullptr, nullptr, qb, M_, 3*D_, D_);
  attn_k<<<dim3(16,32), blk, 0, stream>>>(qb, qb + (size_t)M_*D_, qb + 2*(size_t)M_*D_, ctx);
  gemm_k<2><<<dim3(8,32),  blk, 0, stream>>>(ctx, woT, bo, x, x1, M_, D_, D_);
  ln_kernel<<<M_, blk, 0, stream>>>(x1, ln2s, ln2b, h2);
  gemm_k<3><<<dim3(32,32), blk, 0, stream>>>(h2, w1T, b1, nullptr, ff1, M_, DFF_, D_);
  gemm_k<2><<<dim3(8,32),  blk, 0, stream>>>(ff1, w2T, b2, x1, out, M_, D_, DFF_);
}

// Round 3
// 318.216 us; speedup vs baseline: 1.9455x; 1.9455x over previous
//
#include <hip/hip_runtime.h>
#include <hip/hip_bf16.h>
#include <stdint.h>

typedef unsigned short u16;
typedef __attribute__((ext_vector_type(8))) short s16x8;   // 8 bf16 (4 VGPRs) — MFMA A/B frag
typedef __attribute__((ext_vector_type(4))) float f32x4;   // MFMA C/D frag

#define B_   2
#define T_   2048
#define D_   1024
#define H_   16
#define HD_  64
#define DFF_ 4096
#define M_   (B_*T_)   // 4096

// ---------- helpers ----------
__device__ __forceinline__ u16 f2b(float f){          // fp32 -> bf16, RNE
  uint32_t u = __float_as_uint(f);
  u += 0x7FFFu + ((u >> 16) & 1u);
  return (u16)(u >> 16);
}

// async global->LDS, 16B per lane. LDS dest is wave-uniform-base + lane*16 (lane-linear).
__device__ __forceinline__ void gl_lds16(const void* g, void* l){
  __builtin_amdgcn_global_load_lds((const __attribute__((address_space(1))) void*)g,
                                   (__attribute__((address_space(3))) void*)l, 16, 0, 0);
}

// ---------- weight fp32 [K][N] -> bf16 transposed [N][K] ----------
__global__ __launch_bounds__(256) void wconv(const float* __restrict__ W, u16* __restrict__ Wt,
                                             int K, int N){
  const int k0 = blockIdx.x << 6, n0 = blockIdx.y << 6;
  __shared__ u16 tile[64][68];
  const int tid = threadIdx.x;
  const int rr = tid >> 4, c4 = (tid & 15) << 2;
  #pragma unroll
  for (int rep = 0; rep < 4; rep++){
    int r = rr + (rep << 4);
    float4 v = *reinterpret_cast<const float4*>(W + (size_t)(k0 + r)*N + n0 + c4);
    tile[r][c4+0] = f2b(v.x); tile[r][c4+1] = f2b(v.y);
    tile[r][c4+2] = f2b(v.z); tile[r][c4+3] = f2b(v.w);
  }
  __syncthreads();
  const int rn = tid >> 2, kb = (tid & 3) << 4;
  u16 tmp[16];
  #pragma unroll
  for (int j = 0; j < 16; j++) tmp[j] = tile[kb + j][rn];
  ushort4* dst = reinterpret_cast<ushort4*>(Wt + (size_t)(n0 + rn)*K + k0 + kb);
  dst[0] = make_ushort4(tmp[0], tmp[1], tmp[2], tmp[3]);
  dst[1] = make_ushort4(tmp[4], tmp[5], tmp[6], tmp[7]);
  dst[2] = make_ushort4(tmp[8], tmp[9], tmp[10], tmp[11]);
  dst[3] = make_ushort4(tmp[12], tmp[13], tmp[14], tmp[15]);
}

// ---------- LayerNorm: fp32 [rows][1024] -> bf16 ----------
__global__ __launch_bounds__(256) void ln_kernel(const float* __restrict__ X,
                                                 const float* __restrict__ sc,
                                                 const float* __restrict__ sh,
                                                 u16* __restrict__ out){
  const int row = blockIdx.x;
  const int tid = threadIdx.x;
  const float* xr = X + ((size_t)row << 10);
  float4 a = reinterpret_cast<const float4*>(xr)[tid];
  float s = a.x + a.y + a.z + a.w;
  float q = a.x*a.x + a.y*a.y + a.z*a.z + a.w*a.w;
  #pragma unroll
  for (int o = 32; o > 0; o >>= 1){ s += __shfl_xor(s, o); q += __shfl_xor(q, o); }
  __shared__ float red[8];
  const int w = tid >> 6;
  if ((tid & 63) == 0){ red[w] = s; red[4 + w] = q; }
  __syncthreads();
  float S = red[0] + red[1] + red[2] + red[3];
  float Q = red[4] + red[5] + red[6] + red[7];
  float mean = S * (1.0f/1024.0f);
  float var  = Q * (1.0f/1024.0f) - mean*mean;
  float inv = rsqrtf(var + 1e-5f);
  float4 gsc = reinterpret_cast<const float4*>(sc)[tid];
  float4 gsh = reinterpret_cast<const float4*>(sh)[tid];
  ushort4 o4;
  o4.x = f2b((a.x - mean)*inv*gsc.x + gsh.x);
  o4.y = f2b((a.y - mean)*inv*gsc.y + gsh.y);
  o4.z = f2b((a.z - mean)*inv*gsc.z + gsh.z);
  o4.w = f2b((a.w - mean)*inv*gsc.w + gsh.w);
  reinterpret_cast<ushort4*>(out + ((size_t)row << 10))[tid] = o4;
}

// ---------- split-K reduce: out[m][n] = p0 + p1 + bias[n] + resid[m][n] (all fp32, N=1024) ----------
__global__ __launch_bounds__(256) void reduce2(const float* __restrict__ p,
                                               const float* __restrict__ bias,
                                               const float* __restrict__ resid,
                                               float* __restrict__ out){
  const size_t idx = ((size_t)blockIdx.x << 8) + threadIdx.x;      // float4 index
  float4 a = reinterpret_cast<const float4*>(p)[idx];
  float4 b = reinterpret_cast<const float4*>(p)[idx + (((size_t)M_*D_) >> 2)];
  float4 r = reinterpret_cast<const float4*>(resid)[idx];
  float4 bb = reinterpret_cast<const float4*>(bias)[threadIdx.x];
  float4 o;
  o.x = a.x + b.x + r.x + bb.x;
  o.y = a.y + b.y + r.y + bb.y;
  o.z = a.z + b.z + r.z + bb.z;
  o.w = a.w + b.w + r.w + bb.w;
  reinterpret_cast<float4*>(out)[idx] = o;
}

// ---------- bf16 GEMM: C[M,N] = A[M,K(lda)] @ Bt[N,K(lda)]^T, 128x128 tile, BK=32 ----------
// EPI 0: raw fp32 partial (split-K via gridDim.z: A/Bt column-offset by z*K, Cv offset z*M*N)
// EPI 1: QKV scatter to [3][B][H][T][HD] bf16 (N must be 3072)
// EPI 3: gelu_tanh(+bias[n]) -> bf16 [M][N]
template<int EPI>
__global__ __launch_bounds__(256) void gemm_k(const u16* __restrict__ A, const u16* __restrict__ Bt,
                                              const float* __restrict__ bias,
                                              void* __restrict__ Cv, int M, int N, int K, int lda){
  __shared__ __align__(16) u16 As[128*32];
  __shared__ __align__(16) u16 Bs[128*32];
  const int tid = threadIdx.x;
  const int lane = tid & 63;
  const int w = tid >> 6;
  const int wr = w >> 1, wc = w & 1;           // 2x2 waves, each owns 64x64
  const int g = lane >> 4, l15 = lane & 15;
  const int tn0 = blockIdx.x << 7;
  const int tm0 = blockIdx.y << 7;
  const int kz = blockIdx.z;                   // split-K slice
  const u16* Az = A  + (size_t)kz * K;
  const u16* Bz = Bt + (size_t)kz * K;

  f32x4 acc[4][4];
  #pragma unroll
  for (int i = 0; i < 4; i++)
    #pragma unroll
    for (int j = 0; j < 4; j++) acc[i][j] = (f32x4){0.f,0.f,0.f,0.f};

  const int ch0 = tid, ch1 = 256 + tid;
  const int r0 = ch0 >> 2, c0 = (((ch0 & 3) ^ ((r0 >> 1) & 3)) << 3);
  const int r1 = ch1 >> 2, c1 = (((ch1 & 3) ^ ((r1 >> 1) & 3)) << 3);
  const u16* A0 = Az + (size_t)(tm0 + r0)*lda + c0;
  const u16* A1 = Az + (size_t)(tm0 + r1)*lda + c1;
  const u16* B0 = Bz + (size_t)(tn0 + r0)*lda + c0;
  const u16* B1 = Bz + (size_t)(tn0 + r1)*lda + c1;
  u16* lA0 = As + ch0*8; u16* lA1 = As + ch1*8;
  u16* lB0 = Bs + ch0*8; u16* lB1 = Bs + ch1*8;

  for (int kt = 0; kt < K; kt += 32){
    gl_lds16(A0 + kt, lA0);
    gl_lds16(A1 + kt, lA1);
    gl_lds16(B0 + kt, lB0);
    gl_lds16(B1 + kt, lB1);
    __syncthreads();
    s16x8 af[4], bf[4];
    #pragma unroll
    for (int i = 0; i < 4; i++){
      int ra = (wr << 6) + (i << 4) + l15;
      af[i] = *reinterpret_cast<const s16x8*>(As + ra*32 + ((g ^ ((ra >> 1) & 3)) << 3));
    }
    #pragma unroll
    for (int j = 0; j < 4; j++){
      int rb = (wc << 6) + (j << 4) + l15;
      bf[j] = *reinterpret_cast<const s16x8*>(Bs + rb*32 + ((g ^ ((rb >> 1) & 3)) << 3));
    }
    #pragma unroll
    for (int i = 0; i < 4; i++)
      #pragma unroll
      for (int j = 0; j < 4; j++)
        acc[i][j] = __builtin_amdgcn_mfma_f32_16x16x32_bf16(af[i], bf[j], acc[i][j], 0, 0, 0);
    __syncthreads();
  }

  #pragma unroll
  for (int i = 0; i < 4; i++){
    const int mb = tm0 + (wr << 6) + (i << 4) + (g << 2);
    #pragma unroll
    for (int j = 0; j < 4; j++){
      const int n = tn0 + (wc << 6) + (j << 4) + l15;
      #pragma unroll
      for (int rr = 0; rr < 4; rr++){
        const int m = mb + rr;
        float v = acc[i][j][rr];
        if constexpr (EPI == 0){
          ((float*)Cv)[(size_t)kz*((size_t)M*N) + (size_t)m*N + n] = v;
        } else if constexpr (EPI == 1){
          const int sel = n >> 10, nn = n & 1023;
          const int hh = nn >> 6, d = nn & 63;
          ((u16*)Cv)[(size_t)sel*((size_t)M_*D_) +
                     ((((size_t)(m >> 11)*H_ + hh)*T_ + (m & 2047)) << 6) + d] = f2b(v);
        } else {
          float u = v + bias[n];
          float t2 = 0.7978845608f*(u + 0.044715f*u*u*u);
          float e = __expf(2.0f*t2);
          float th = 1.0f - 2.0f/(e + 1.0f);
          ((u16*)Cv)[(size_t)m*N + n] = f2b(0.5f*u*(1.0f + th));
        }
      }
    }
  }
}

// ---------- causal flash attention, v3 ----------
// grid (pair=16, bh=32): block p does q-tiles {p, 31-p} -> 33 k-tiles each, 512 uniform blocks.
// Double-buffered K/V, ONE barrier per k-tile (end-of-iter). ALL array indices static (rule #20);
// bank conflicts handled purely by XOR chunk swizzles:
//   Q/K : chunk ^= (row&7)                                  (gl_lds pre-swizzled global source)
//   Vt  : chunk ^= (d&7) ^ ((d>>4)<<1)    [Vt is V^T: row=d, 8 chunks of 8 k-values]
//   Pl  : chunk ^= (prow&7) ^ ((prow>>3)<<1)
__global__ __launch_bounds__(256) void attn_k(const u16* __restrict__ Qg, const u16* __restrict__ Kg,
                                              const u16* __restrict__ Vg, u16* __restrict__ ctx){
  const int pr_ = blockIdx.x;
  const int bh  = blockIdx.y;
  const int tid = threadIdx.x;
  const int lane = tid & 63;
  const int w = tid >> 6;
  const int g = lane >> 4, l15 = lane & 15;

  __shared__ __align__(16) u16 Qs[64*64];
  __shared__ __align__(16) u16 Ks[2][64*64];
  __shared__ __align__(16) u16 Vt[2][64*64];
  __shared__ __align__(16) u16 Pl[4][16*64];

  const size_t hb = (size_t)bh * ((size_t)T_*HD_);
  const u16* Qh = Qg + hb;
  const u16* Kh = Kg + hb;
  const u16* Vh = Vg + hb;
  const int b = bh >> 4, hh = bh & 15;

  const int s_r0 = tid >> 3,        s_c0 = (((tid & 7) ^ (s_r0 & 7)) << 3);
  const int s_r1 = (256+tid) >> 3,  s_c1 = ((((256+tid) & 7) ^ (s_r1 & 7)) << 3);
  const int v_kr = tid >> 2, v_d0 = (tid & 3) << 4;

  const float SC2 = 0.18033688f;                 // (1/8) * log2(e)

#define SINK_V(buf, q0, q1, q2, q3) do {                                          \
    u16 vv[16] = {q0.x,q0.y,q0.z,q0.w, q1.x,q1.y,q1.z,q1.w,                       \
                  q2.x,q2.y,q2.z,q2.w, q3.x,q3.y,q3.z,q3.w};                      \
    _Pragma("unroll")                                                             \
    for (int j = 0; j < 16; j++){                                                 \
      int d = v_d0 + j;                                                           \
      Vt[buf][d*64 + ((((v_kr >> 3) ^ (d & 7) ^ ((d >> 4) << 1)) & 7) << 3)       \
              + (v_kr & 7)] = vv[j];                                              \
    }                                                                             \
  } while (0)

  for (int ph = 0; ph < 2; ++ph){
    const int qt = ph ? (31 - pr_) : pr_;

    // stage Q + K tile0 (async DMA), V tile0 (reg path, static sink)
    gl_lds16(Qh + (size_t)(qt*64 + s_r0)*HD_ + s_c0, Qs + tid*8);
    gl_lds16(Qh + (size_t)(qt*64 + s_r1)*HD_ + s_c1, Qs + (256+tid)*8);
    gl_lds16(Kh + (size_t)(s_r0)*HD_ + s_c0, Ks[0] + tid*8);
    gl_lds16(Kh + (size_t)(s_r1)*HD_ + s_c1, Ks[0] + (256+tid)*8);
    {
      const u16* vs = Vh + (size_t)v_kr*HD_ + v_d0;
      ushort4 a0 = *(const ushort4*)(vs + 0);
      ushort4 a1 = *(const ushort4*)(vs + 4);
      ushort4 a2 = *(const ushort4*)(vs + 8);
      ushort4 a3 = *(const ushort4*)(vs + 12);
      SINK_V(0, a0, a1, a2, a3);
    }
    __syncthreads();                             // drain DMA + V writes visible

    s16x8 qa[2];
    #pragma unroll
    for (int kk = 0; kk < 2; kk++){
      int ra = (w << 4) + l15;
      int slot = (kk << 2) + g;
      qa[kk] = *reinterpret_cast<const s16x8*>(Qs + ra*64 + ((slot ^ (ra & 7)) << 3));
    }

    f32x4 accO[4];
    #pragma unroll
    for (int j = 0; j < 4; j++) accO[j] = (f32x4){0.f,0.f,0.f,0.f};
    float mrow[4] = {-1e30f,-1e30f,-1e30f,-1e30f};
    float lrow[4] = {0.f,0.f,0.f,0.f};

    for (int kt = 0; kt <= qt; ++kt){
      const int cur = kt & 1, nxt = cur ^ 1;
      const bool pf = (kt < qt);

      // ---- prefetch tile kt+1: K async->LDS[nxt]; V global->reg (sink after PV)
      ushort4 p0, p1, p2, p3;
      if (pf){
        gl_lds16(Kh + (size_t)((kt+1)*64 + s_r0)*HD_ + s_c0, Ks[nxt] + tid*8);
        gl_lds16(Kh + (size_t)((kt+1)*64 + s_r1)*HD_ + s_c1, Ks[nxt] + (256+tid)*8);
        const u16* vs = Vh + (size_t)((kt+1)*64 + v_kr)*HD_ + v_d0;
        p0 = *(const ushort4*)(vs + 0);
        p1 = *(const ushort4*)(vs + 4);
        p2 = *(const ushort4*)(vs + 8);
        p3 = *(const ushort4*)(vs + 12);
      }

      // ---- S = Q K^T from Ks[cur]
      f32x4 accS[4];
      #pragma unroll
      for (int j = 0; j < 4; j++) accS[j] = (f32x4){0.f,0.f,0.f,0.f};
      #pragma unroll
      for (int jn = 0; jn < 4; jn++){
        #pragma unroll
        for (int kk = 0; kk < 2; kk++){
          int rb = (jn << 4) + l15;
          int slot = (kk << 2) + g;
          s16x8 kf = *reinterpret_cast<const s16x8*>(Ks[cur] + rb*64 + ((slot ^ (rb & 7)) << 3));
          accS[jn] = __builtin_amdgcn_mfma_f32_16x16x32_bf16(qa[kk], kf, accS[jn], 0, 0, 0);
        }
      }

      // ---- scale to log2 domain + causal mask (diagonal tile only)
      float sv[4][4];
      #pragma unroll
      for (int jn = 0; jn < 4; jn++)
        #pragma unroll
        for (int rr = 0; rr < 4; rr++){
          float xv = accS[jn][rr] * SC2;
          if (kt == qt){
            int qrow = (w << 4) + (g << 2) + rr;
            int kcol = (jn << 4) + l15;
            if (kcol > qrow) xv = -1e30f;
          }
          sv[jn][rr] = xv;
        }

      // ---- online softmax (exp2 domain); row r = 4g+rr lives in lanes [16g..16g+15]
      float sf[4];
      #pragma unroll
      for (int rr = 0; rr < 4; rr++){
        float t = fmaxf(fmaxf(sv[0][rr], sv[1][rr]), fmaxf(sv[2][rr], sv[3][rr]));
        t = fmaxf(t, __shfl_xor(t, 1));
        t = fmaxf(t, __shfl_xor(t, 2));
        t = fmaxf(t, __shfl_xor(t, 4));
        t = fmaxf(t, __shfl_xor(t, 8));
        float mn = fmaxf(mrow[rr], t);
        sf[rr] = exp2f(mrow[rr] - mn);
        mrow[rr] = mn;
      }
      float tsum[4] = {0.f,0.f,0.f,0.f};
      #pragma unroll
      for (int jn = 0; jn < 4; jn++){
        #pragma unroll
        for (int rr = 0; rr < 4; rr++){
          float pv = exp2f(sv[jn][rr] - mrow[rr]);
          tsum[rr] += pv;
          int prow = (g << 2) + rr;
          int pcol = (jn << 4) + l15;
          Pl[w][prow*64 + ((((pcol >> 3) ^ (prow & 7) ^ ((prow >> 3) << 1)) & 7) << 3)
                + (pcol & 7)] = f2b(pv);
        }
      }
      #pragma unroll
      for (int rr = 0; rr < 4; rr++){
        float t = tsum[rr];
        t += __shfl_xor(t, 1);
        t += __shfl_xor(t, 2);
        t += __shfl_xor(t, 4);
        t += __shfl_xor(t, 8);
        lrow[rr] = lrow[rr]*sf[rr] + t;
        #pragma unroll
        for (int jn = 0; jn < 4; jn++) accO[jn][rr] *= sf[rr];
      }
      // P is per-wave: same-wave LDS write->read ordered by lgkmcnt, no barrier needed.

      // ---- O += P V from Vt[cur]
      #pragma unroll
      for (int kk = 0; kk < 2; kk++){
        int slot = (kk << 2) + g;
        s16x8 pa = *reinterpret_cast<const s16x8*>(
            &Pl[w][l15*64 + (((slot ^ (l15 & 7) ^ ((l15 >> 3) << 1)) & 7) << 3)]);
        #pragma unroll
        for (int jn = 0; jn < 4; jn++){
          int vd = (jn << 4) + l15;
          s16x8 vbf = *reinterpret_cast<const s16x8*>(
              Vt[cur] + vd*64 + (((slot ^ (vd & 7) ^ ((vd >> 4) << 1)) & 7) << 3));
          accO[jn] = __builtin_amdgcn_mfma_f32_16x16x32_bf16(pa, vbf, accO[jn], 0, 0, 0);
        }
      }

      // ---- sink prefetched V into Vt[nxt]; barrier closes the iteration
      if (pf) SINK_V(nxt, p0, p1, p2, p3);
      __syncthreads();
    }

    // ---- epilogue: O/l -> ctx[(b*T+q)*D + h*64 + d]  (no LDS touched)
    #pragma unroll
    for (int rr = 0; rr < 4; rr++){
      float inv = 1.0f / lrow[rr];
      int qrow = qt*64 + (w << 4) + (g << 2) + rr;
      size_t rowbase = ((size_t)(b*T_ + qrow) << 10) + ((size_t)hh << 6);
      #pragma unroll
      for (int jn = 0; jn < 4; jn++){
        int d = (jn << 4) + l15;
        ctx[rowbase + d] = f2b(accO[jn][rr] * inv);
      }
    }
  }
#undef SINK_V
}

// ---------- launch ----------
extern "C" void kernel_launch(void* const* d_in, const int* in_sizes, int n_in,
                              void* d_out, int out_size, void* d_ws, size_t ws_size,
                              hipStream_t stream){
  (void)in_sizes; (void)n_in; (void)out_size; (void)ws_size;
  const float* x    = (const float*)d_in[0];
  const float* wq   = (const float*)d_in[1];
  const float* wk   = (const float*)d_in[2];
  const float* wv   = (const float*)d_in[3];
  const float* wo   = (const float*)d_in[4];
  const float* bo   = (const float*)d_in[5];
  const float* ln1s = (const float*)d_in[6];
  const float* ln1b = (const float*)d_in[7];
  const float* ln2s = (const float*)d_in[8];
  const float* ln2b = (const float*)d_in[9];
  const float* w1   = (const float*)d_in[10];
  const float* b1   = (const float*)d_in[11];
  const float* w2   = (const float*)d_in[12];
  const float* b2   = (const float*)d_in[13];
  float* out = (float*)d_out;

  char* p = (char*)d_ws;
  u16*  wqkvT = (u16*)p;  p += (size_t)3*D_*D_*2;
  u16*  woT   = (u16*)p;  p += (size_t)D_*D_*2;
  u16*  w1T   = (u16*)p;  p += (size_t)D_*DFF_*2;
  u16*  w2T   = (u16*)p;  p += (size_t)DFF_*D_*2;
  u16*  h     = (u16*)p;  p += (size_t)M_*D_*2;
  u16*  qb    = (u16*)p;  p += (size_t)M_*D_*2;
  u16*  kb    = (u16*)p;  p += (size_t)M_*D_*2;
  u16*  vb    = (u16*)p;  p += (size_t)M_*D_*2;
  u16*  ctx   = (u16*)p;  p += (size_t)M_*D_*2;
  float* x1   = (float*)p; p += (size_t)M_*D_*4;
  u16*  h2    = (u16*)p;  p += (size_t)M_*D_*2;
  u16*  ff1   = (u16*)p;  p += (size_t)M_*DFF_*2;
  (void)kb; (void)vb;
  // split-K partial buffer: [2][M][1024] fp32 = 32MB, recycled over dead h..vb region
  float* part = (float*)h;

  dim3 blk(256);
  wconv<<<dim3(16,16), blk, 0, stream>>>(wq, wqkvT + 0*(size_t)D_*D_, D_, D_);
  wconv<<<dim3(16,16), blk, 0, stream>>>(wk, wqkvT + 1*(size_t)D_*D_, D_, D_);
  wconv<<<dim3(16,16), blk, 0, stream>>>(wv, wqkvT + 2*(size_t)D_*D_, D_, D_);
  wconv<<<dim3(16,16), blk, 0, stream>>>(wo, woT, D_, D_);
  wconv<<<dim3(16,64), blk, 0, stream>>>(w1, w1T, D_, DFF_);
  wconv<<<dim3(64,16), blk, 0, stream>>>(w2, w2T, DFF_, D_);

  ln_kernel<<<M_, blk, 0, stream>>>(x, ln1s, ln1b, h);
  gemm_k<1><<<dim3(24,32,1), blk, 0, stream>>>(h, wqkvT, nullptr, qb, M_, 3*D_, D_, D_);
  attn_k<<<dim3(16,32), blk, 0, stream>>>(qb, qb + (size_t)M_*D_, qb + 2*(size_t)M_*D_, ctx);
  // WO: split-K x2 (K=1024 -> 2x512), 512 blocks
  gemm_k<0><<<dim3(8,32,2), blk, 0, stream>>>(ctx, woT, nullptr, part, M_, D_, D_/2, D_);
  reduce2<<<M_, blk, 0, stream>>>(part, bo, x, x1);
  ln_kernel<<<M_, blk, 0, stream>>>(x1, ln2s, ln2b, h2);
  gemm_k<3><<<dim3(32,32,1), blk, 0, stream>>>(h2, w1T, b1, ff1, M_, DFF_, D_, D_);
  // FFN2: split-K x2 (K=4096 -> 2x2048), 512 blocks
  gemm_k<0><<<dim3(8,32,2), blk, 0, stream>>>(ff1, w2T, nullptr, part, M_, D_, DFF_/2, DFF_);
  reduce2<<<M_, blk, 0, stream>>>(part, b2, x1, out);
}

// Round 4
// 282.665 us; speedup vs baseline: 2.1902x; 1.1258x over previous
//
#include <hip/hip_runtime.h>
#include <hip/hip_bf16.h>
#include <stdint.h>

typedef unsigned short u16;
typedef __attribute__((ext_vector_type(8))) short s16x8;   // 8 bf16 (4 VGPRs) — MFMA A/B frag
typedef __attribute__((ext_vector_type(4))) float f32x4;   // MFMA C/D frag

#define B_   2
#define T_   2048
#define D_   1024
#define H_   16
#define HD_  64
#define DFF_ 4096
#define M_   (B_*T_)   // 4096

#define SC2F 0.18033688f   // (1/8) * log2(e) — folded into Q at QKV epilogue

// ---------- helpers ----------
__device__ __forceinline__ u16 f2b(float f){          // fp32 -> bf16, RNE
  uint32_t u = __float_as_uint(f);
  u += 0x7FFFu + ((u >> 16) & 1u);
  return (u16)(u >> 16);
}

// async global->LDS, 16B per lane. LDS dest is wave-uniform-base + lane*16 (lane-linear).
__device__ __forceinline__ void gl_lds16(const void* g, void* l){
  __builtin_amdgcn_global_load_lds((const __attribute__((address_space(1))) void*)g,
                                   (__attribute__((address_space(3))) void*)l, 16, 0, 0);
}

// ---------- ALL weight conversions fp32 [K][N] -> bf16 [N][K], one launch ----------
__global__ __launch_bounds__(256) void wconv_all(const float* __restrict__ wq,
                                                 const float* __restrict__ wk,
                                                 const float* __restrict__ wv,
                                                 const float* __restrict__ wo,
                                                 const float* __restrict__ w1,
                                                 const float* __restrict__ w2,
                                                 u16* __restrict__ wqkvT, u16* __restrict__ woT,
                                                 u16* __restrict__ w1T,   u16* __restrict__ w2T){
  const int bid = blockIdx.x;
  const float* W; u16* Wt; int K, N, tk, tn;
  if (bid < 1024){
    const int which = bid >> 8, t = bid & 255; tk = t >> 4; tn = t & 15; K = 1024; N = 1024;
    W  = (which == 0) ? wq : (which == 1) ? wk : (which == 2) ? wv : wo;
    Wt = (which == 3) ? woT : wqkvT + (size_t)which * D_ * D_;
  } else if (bid < 2048){
    const int t = bid - 1024; tk = t >> 6; tn = t & 63; K = 1024; N = 4096; W = w1; Wt = w1T;
  } else {
    const int t = bid - 2048; tk = t >> 4; tn = t & 15; K = 4096; N = 1024; W = w2; Wt = w2T;
  }
  const int k0 = tk << 6, n0 = tn << 6;
  __shared__ u16 tile[64][68];
  const int tid = threadIdx.x;
  const int rr = tid >> 4, c4 = (tid & 15) << 2;
  #pragma unroll
  for (int rep = 0; rep < 4; rep++){
    int r = rr + (rep << 4);
    float4 v = *reinterpret_cast<const float4*>(W + (size_t)(k0 + r)*N + n0 + c4);
    tile[r][c4+0] = f2b(v.x); tile[r][c4+1] = f2b(v.y);
    tile[r][c4+2] = f2b(v.z); tile[r][c4+3] = f2b(v.w);
  }
  __syncthreads();
  const int rn = tid >> 2, kb = (tid & 3) << 4;
  u16 tmp[16];
  #pragma unroll
  for (int j = 0; j < 16; j++) tmp[j] = tile[kb + j][rn];
  ushort4* dst = reinterpret_cast<ushort4*>(Wt + (size_t)(n0 + rn)*K + k0 + kb);
  dst[0] = make_ushort4(tmp[0], tmp[1], tmp[2], tmp[3]);
  dst[1] = make_ushort4(tmp[4], tmp[5], tmp[6], tmp[7]);
  dst[2] = make_ushort4(tmp[8], tmp[9], tmp[10], tmp[11]);
  dst[3] = make_ushort4(tmp[12], tmp[13], tmp[14], tmp[15]);
}

// ---------- LayerNorm: fp32 [rows][1024] -> bf16 ----------
__global__ __launch_bounds__(256) void ln_kernel(const float* __restrict__ X,
                                                 const float* __restrict__ sc,
                                                 const float* __restrict__ sh,
                                                 u16* __restrict__ out){
  const int row = blockIdx.x;
  const int tid = threadIdx.x;
  float4 a = reinterpret_cast<const float4*>(X + ((size_t)row << 10))[tid];
  float s = a.x + a.y + a.z + a.w;
  float q = a.x*a.x + a.y*a.y + a.z*a.z + a.w*a.w;
  #pragma unroll
  for (int o = 32; o > 0; o >>= 1){ s += __shfl_xor(s, o); q += __shfl_xor(q, o); }
  __shared__ float red[8];
  const int w = tid >> 6;
  if ((tid & 63) == 0){ red[w] = s; red[4 + w] = q; }
  __syncthreads();
  float S = red[0] + red[1] + red[2] + red[3];
  float Q = red[4] + red[5] + red[6] + red[7];
  float mean = S * (1.0f/1024.0f);
  float var  = Q * (1.0f/1024.0f) - mean*mean;
  float inv = rsqrtf(var + 1e-5f);
  float4 gsc = reinterpret_cast<const float4*>(sc)[tid];
  float4 gsh = reinterpret_cast<const float4*>(sh)[tid];
  ushort4 o4;
  o4.x = f2b((a.x - mean)*inv*gsc.x + gsh.x);
  o4.y = f2b((a.y - mean)*inv*gsc.y + gsh.y);
  o4.z = f2b((a.z - mean)*inv*gsc.z + gsh.z);
  o4.w = f2b((a.w - mean)*inv*gsc.w + gsh.w);
  reinterpret_cast<ushort4*>(out + ((size_t)row << 10))[tid] = o4;
}

// ---------- split-K reduce (+bias+resid) -> fp32 out ----------
__global__ __launch_bounds__(256) void reduce2(const float* __restrict__ p,
                                               const float* __restrict__ bias,
                                               const float* __restrict__ resid,
                                               float* __restrict__ out){
  const size_t idx = ((size_t)blockIdx.x << 8) + threadIdx.x;
  float4 a = reinterpret_cast<const float4*>(p)[idx];
  float4 b = reinterpret_cast<const float4*>(p)[idx + (((size_t)M_*D_) >> 2)];
  float4 r = reinterpret_cast<const float4*>(resid)[idx];
  float4 bb = reinterpret_cast<const float4*>(bias)[threadIdx.x];
  float4 o;
  o.x = a.x + b.x + r.x + bb.x;
  o.y = a.y + b.y + r.y + bb.y;
  o.z = a.z + b.z + r.z + bb.z;
  o.w = a.w + b.w + r.w + bb.w;
  reinterpret_cast<float4*>(out)[idx] = o;
}

// ---------- fused: split-K reduce (+bo+resid) -> x1 fp32  AND  LayerNorm2 -> h2 bf16 ----------
__global__ __launch_bounds__(256) void reduce_ln(const float* __restrict__ p,
                                                 const float* __restrict__ bias,
                                                 const float* __restrict__ resid,
                                                 const float* __restrict__ sc,
                                                 const float* __restrict__ sh,
                                                 float* __restrict__ x1,
                                                 u16* __restrict__ h2){
  const int row = blockIdx.x;
  const int tid = threadIdx.x;
  const size_t idx = ((size_t)row << 8) + tid;
  float4 a  = reinterpret_cast<const float4*>(p)[idx];
  float4 b  = reinterpret_cast<const float4*>(p)[idx + (((size_t)M_*D_) >> 2)];
  float4 r  = reinterpret_cast<const float4*>(resid)[idx];
  float4 bb = reinterpret_cast<const float4*>(bias)[tid];
  float4 v;
  v.x = a.x + b.x + r.x + bb.x;
  v.y = a.y + b.y + r.y + bb.y;
  v.z = a.z + b.z + r.z + bb.z;
  v.w = a.w + b.w + r.w + bb.w;
  reinterpret_cast<float4*>(x1)[idx] = v;
  float s = v.x + v.y + v.z + v.w;
  float q = v.x*v.x + v.y*v.y + v.z*v.z + v.w*v.w;
  #pragma unroll
  for (int o = 32; o > 0; o >>= 1){ s += __shfl_xor(s, o); q += __shfl_xor(q, o); }
  __shared__ float red[8];
  const int w = tid >> 6;
  if ((tid & 63) == 0){ red[w] = s; red[4 + w] = q; }
  __syncthreads();
  float S = red[0] + red[1] + red[2] + red[3];
  float Q = red[4] + red[5] + red[6] + red[7];
  float mean = S * (1.0f/1024.0f);
  float var  = Q * (1.0f/1024.0f) - mean*mean;
  float inv = rsqrtf(var + 1e-5f);
  float4 gsc = reinterpret_cast<const float4*>(sc)[tid];
  float4 gsh = reinterpret_cast<const float4*>(sh)[tid];
  ushort4 o4;
  o4.x = f2b((v.x - mean)*inv*gsc.x + gsh.x);
  o4.y = f2b((v.y - mean)*inv*gsc.y + gsh.y);
  o4.z = f2b((v.z - mean)*inv*gsc.z + gsh.z);
  o4.w = f2b((v.w - mean)*inv*gsc.w + gsh.w);
  reinterpret_cast<ushort4*>(h2 + ((size_t)row << 10))[tid] = o4;
}

// ---------- bf16 GEMM: C[M,N] = A[M,K(lda)] @ Bt[N,K(lda)]^T, 128x128 tile, BK=32 ----------
// EPI 0: raw fp32 partial (split-K via gridDim.z)
// EPI 1: QKV scatter to [3][B][H][T][HD] bf16; Q part pre-scaled by SC2F
// EPI 3: gelu_tanh(+bias[n]) -> bf16 [M][N]
template<int EPI>
__global__ __launch_bounds__(256) void gemm_k(const u16* __restrict__ A, const u16* __restrict__ Bt,
                                              const float* __restrict__ bias,
                                              void* __restrict__ Cv, int M, int N, int K, int lda){
  __shared__ __align__(16) u16 As[128*32];
  __shared__ __align__(16) u16 Bs[128*32];
  const int tid = threadIdx.x;
  const int lane = tid & 63;
  const int w = tid >> 6;
  const int wr = w >> 1, wc = w & 1;
  const int g = lane >> 4, l15 = lane & 15;
  const int tn0 = blockIdx.x << 7;
  const int tm0 = blockIdx.y << 7;
  const int kz = blockIdx.z;
  const u16* Az = A  + (size_t)kz * K;
  const u16* Bz = Bt + (size_t)kz * K;

  f32x4 acc[4][4];
  #pragma unroll
  for (int i = 0; i < 4; i++)
    #pragma unroll
    for (int j = 0; j < 4; j++) acc[i][j] = (f32x4){0.f,0.f,0.f,0.f};

  const int ch0 = tid, ch1 = 256 + tid;
  const int r0 = ch0 >> 2, c0 = (((ch0 & 3) ^ ((r0 >> 1) & 3)) << 3);
  const int r1 = ch1 >> 2, c1 = (((ch1 & 3) ^ ((r1 >> 1) & 3)) << 3);
  const u16* A0 = Az + (size_t)(tm0 + r0)*lda + c0;
  const u16* A1 = Az + (size_t)(tm0 + r1)*lda + c1;
  const u16* B0 = Bz + (size_t)(tn0 + r0)*lda + c0;
  const u16* B1 = Bz + (size_t)(tn0 + r1)*lda + c1;
  u16* lA0 = As + ch0*8; u16* lA1 = As + ch1*8;
  u16* lB0 = Bs + ch0*8; u16* lB1 = Bs + ch1*8;

  for (int kt = 0; kt < K; kt += 32){
    gl_lds16(A0 + kt, lA0);
    gl_lds16(A1 + kt, lA1);
    gl_lds16(B0 + kt, lB0);
    gl_lds16(B1 + kt, lB1);
    __syncthreads();
    s16x8 af[4], bf[4];
    #pragma unroll
    for (int i = 0; i < 4; i++){
      int ra = (wr << 6) + (i << 4) + l15;
      af[i] = *reinterpret_cast<const s16x8*>(As + ra*32 + ((g ^ ((ra >> 1) & 3)) << 3));
    }
    #pragma unroll
    for (int j = 0; j < 4; j++){
      int rb = (wc << 6) + (j << 4) + l15;
      bf[j] = *reinterpret_cast<const s16x8*>(Bs + rb*32 + ((g ^ ((rb >> 1) & 3)) << 3));
    }
    #pragma unroll
    for (int i = 0; i < 4; i++)
      #pragma unroll
      for (int j = 0; j < 4; j++)
        acc[i][j] = __builtin_amdgcn_mfma_f32_16x16x32_bf16(af[i], bf[j], acc[i][j], 0, 0, 0);
    __syncthreads();
  }

  #pragma unroll
  for (int i = 0; i < 4; i++){
    const int mb = tm0 + (wr << 6) + (i << 4) + (g << 2);
    #pragma unroll
    for (int j = 0; j < 4; j++){
      const int n = tn0 + (wc << 6) + (j << 4) + l15;
      #pragma unroll
      for (int rr = 0; rr < 4; rr++){
        const int m = mb + rr;
        float v = acc[i][j][rr];
        if constexpr (EPI == 0){
          ((float*)Cv)[(size_t)kz*((size_t)M*N) + (size_t)m*N + n] = v;
        } else if constexpr (EPI == 1){
          const int sel = n >> 10, nn = n & 1023;
          const int hh = nn >> 6, d = nn & 63;
          if (sel == 0) v *= SC2F;                     // pre-scale Q for exp2-domain softmax
          ((u16*)Cv)[(size_t)sel*((size_t)M_*D_) +
                     ((((size_t)(m >> 11)*H_ + hh)*T_ + (m & 2047)) << 6) + d] = f2b(v);
        } else {
          float u = v + bias[n];
          float t2 = 0.7978845608f*(u + 0.044715f*u*u*u);
          float e = __expf(2.0f*t2);
          float th = 1.0f - 2.0f/(e + 1.0f);
          ((u16*)Cv)[(size_t)m*N + n] = f2b(0.5f*u*(1.0f + th));
        }
      }
    }
  }
}

// ---------- causal flash attention, v4: swapped QK^T (S^T), lane-local softmax ----------
// grid (pair=16, bh=32); block p -> q-tiles {p, 31-p} (33 k-tiles each, uniform).
// S^T = mfma(K_frag, Q_frag): identical LDS reads as v3, only operand order swapped.
// Thread (g,l15) holds S^T[k=16jn+4g+rr][q=l15]: softmax row-reduce = 15-op reg chain
// + 2 shfl_xor (16,32) instead of 32 bpermutes. m,l scalars. T13 defer-rescale.
// P stored in original [q][k] orientation -> PV path unchanged from v3.
__global__ __launch_bounds__(256) void attn_k(const u16* __restrict__ Qg, const u16* __restrict__ Kg,
                                              const u16* __restrict__ Vg, u16* __restrict__ ctx){
  const int pr_ = blockIdx.x;
  const int bh  = blockIdx.y;
  const int tid = threadIdx.x;
  const int lane = tid & 63;
  const int w = tid >> 6;
  const int g = lane >> 4, l15 = lane & 15;

  __shared__ __align__(16) u16 Qs[64*64];
  __shared__ __align__(16) u16 Ks[2][64*64];
  __shared__ __align__(16) u16 Vt[2][64*64];
  __shared__ __align__(16) u16 Pl[4][16*64];

  const size_t hb = (size_t)bh * ((size_t)T_*HD_);
  const u16* Qh = Qg + hb;
  const u16* Kh = Kg + hb;
  const u16* Vh = Vg + hb;
  const int b = bh >> 4, hh = bh & 15;

  const int s_r0 = tid >> 3,        s_c0 = (((tid & 7) ^ (s_r0 & 7)) << 3);
  const int s_r1 = (256+tid) >> 3,  s_c1 = ((((256+tid) & 7) ^ (s_r1 & 7)) << 3);
  const int v_kr = tid >> 2, v_d0 = (tid & 3) << 4;

#define SINK_V(buf, q0, q1, q2, q3) do {                                          \
    u16 vv[16] = {q0.x,q0.y,q0.z,q0.w, q1.x,q1.y,q1.z,q1.w,                       \
                  q2.x,q2.y,q2.z,q2.w, q3.x,q3.y,q3.z,q3.w};                      \
    _Pragma("unroll")                                                             \
    for (int j = 0; j < 16; j++){                                                 \
      int d = v_d0 + j;                                                           \
      Vt[buf][d*64 + ((((v_kr >> 3) ^ (d & 7) ^ ((d >> 4) << 1)) & 7) << 3)       \
              + (v_kr & 7)] = vv[j];                                              \
    }                                                                             \
  } while (0)

  for (int ph = 0; ph < 2; ++ph){
    const int qt = ph ? (31 - pr_) : pr_;

    gl_lds16(Qh + (size_t)(qt*64 + s_r0)*HD_ + s_c0, Qs + tid*8);
    gl_lds16(Qh + (size_t)(qt*64 + s_r1)*HD_ + s_c1, Qs + (256+tid)*8);
    gl_lds16(Kh + (size_t)(s_r0)*HD_ + s_c0, Ks[0] + tid*8);
    gl_lds16(Kh + (size_t)(s_r1)*HD_ + s_c1, Ks[0] + (256+tid)*8);
    {
      const u16* vs = Vh + (size_t)v_kr*HD_ + v_d0;
      ushort4 a0 = *(const ushort4*)(vs + 0);
      ushort4 a1 = *(const ushort4*)(vs + 4);
      ushort4 a2 = *(const ushort4*)(vs + 8);
      ushort4 a3 = *(const ushort4*)(vs + 12);
      SINK_V(0, a0, a1, a2, a3);
    }
    __syncthreads();

    s16x8 qa[2];
    #pragma unroll
    for (int kk = 0; kk < 2; kk++){
      int ra = (w << 4) + l15;
      int slot = (kk << 2) + g;
      qa[kk] = *reinterpret_cast<const s16x8*>(Qs + ra*64 + ((slot ^ (ra & 7)) << 3));
    }

    f32x4 accO[4];
    #pragma unroll
    for (int j = 0; j < 4; j++) accO[j] = (f32x4){0.f,0.f,0.f,0.f};
    float mrow = -1e30f, lrow = 0.f;            // scalars: this thread's q = 16w + l15
    const int qlt = (w << 4) + l15;             // q local to the tile (for causal mask)

    for (int kt = 0; kt <= qt; ++kt){
      const int cur = kt & 1, nxt = cur ^ 1;
      const bool pf = (kt < qt);

      ushort4 p0, p1, p2, p3;
      if (pf){
        gl_lds16(Kh + (size_t)((kt+1)*64 + s_r0)*HD_ + s_c0, Ks[nxt] + tid*8);
        gl_lds16(Kh + (size_t)((kt+1)*64 + s_r1)*HD_ + s_c1, Ks[nxt] + (256+tid)*8);
        const u16* vs = Vh + (size_t)((kt+1)*64 + v_kr)*HD_ + v_d0;
        p0 = *(const ushort4*)(vs + 0);
        p1 = *(const ushort4*)(vs + 4);
        p2 = *(const ushort4*)(vs + 8);
        p3 = *(const ushort4*)(vs + 12);
      }

      // ---- S^T = K Q^T (swapped operands; reads identical to v3)
      f32x4 accS[4];
      #pragma unroll
      for (int j = 0; j < 4; j++) accS[j] = (f32x4){0.f,0.f,0.f,0.f};
      __builtin_amdgcn_s_setprio(1);
      #pragma unroll
      for (int jn = 0; jn < 4; jn++){
        #pragma unroll
        for (int kk = 0; kk < 2; kk++){
          int rb = (jn << 4) + l15;
          int slot = (kk << 2) + g;
          s16x8 kf = *reinterpret_cast<const s16x8*>(Ks[cur] + rb*64 + ((slot ^ (rb & 7)) << 3));
          accS[jn] = __builtin_amdgcn_mfma_f32_16x16x32_bf16(kf, qa[kk], accS[jn], 0, 0, 0);
        }
      }
      __builtin_amdgcn_s_setprio(0);

      // ---- mask (diagonal tile); values already in log2 domain (Q pre-scaled)
      float sv[4][4];
      #pragma unroll
      for (int jn = 0; jn < 4; jn++)
        #pragma unroll
        for (int rr = 0; rr < 4; rr++){
          float xv = accS[jn][rr];
          if (kt == qt){
            int kl = (jn << 4) + (g << 2) + rr;
            if (kl > qlt) xv = -1e30f;
          }
          sv[jn][rr] = xv;
        }

      // ---- row max: register chain + 2 shuffles (g-groups hold disjoint k-quarters)
      float rmax = sv[0][0];
      #pragma unroll
      for (int jn = 0; jn < 4; jn++)
        #pragma unroll
        for (int rr = 0; rr < 4; rr++) rmax = fmaxf(rmax, sv[jn][rr]);
      rmax = fmaxf(rmax, __shfl_xor(rmax, 16));
      rmax = fmaxf(rmax, __shfl_xor(rmax, 32));

      // ---- T13: rescale only when the running max grew by >8 (log2 domain)
      if (__any(rmax > mrow + 8.0f)){
        float mn = fmaxf(mrow, rmax);
        float sf = exp2f(mrow - mn);
        mrow = mn;
        lrow *= sf;
        #pragma unroll
        for (int rr = 0; rr < 4; rr++){
          float sfr = __shfl(sf, ((lane >> 4) << 2) + rr);   // sf of q-offset 4g+rr
          #pragma unroll
          for (int jn = 0; jn < 4; jn++) accO[jn][rr] *= sfr;
        }
      }

      // ---- P = exp2(S^T - m), store to Pl[q][k] (original orientation; swizzled)
      float tsum = 0.f;
      #pragma unroll
      for (int jn = 0; jn < 4; jn++)
        #pragma unroll
        for (int rr = 0; rr < 4; rr++){
          float pv = exp2f(sv[jn][rr] - mrow);
          tsum += pv;
          int kl = (jn << 4) + (g << 2) + rr;
          int slot = kl >> 3;
          Pl[w][l15*64 + (((slot ^ (l15 & 7)) & 7) << 3) + (kl & 7)] = f2b(pv);
        }
      tsum += __shfl_xor(tsum, 16);
      tsum += __shfl_xor(tsum, 32);
      lrow += tsum;

      // ---- O += P V  (unchanged from v3 except Pl swizzle)
      __builtin_amdgcn_s_setprio(1);
      #pragma unroll
      for (int kk = 0; kk < 2; kk++){
        int slot = (kk << 2) + g;
        s16x8 pa = *reinterpret_cast<const s16x8*>(
            &Pl[w][l15*64 + (((slot ^ (l15 & 7)) & 7) << 3)]);
        #pragma unroll
        for (int jn = 0; jn < 4; jn++){
          int vd = (jn << 4) + l15;
          s16x8 vbf = *reinterpret_cast<const s16x8*>(
              Vt[cur] + vd*64 + (((slot ^ (vd & 7) ^ ((vd >> 4) << 1)) & 7) << 3));
          accO[jn] = __builtin_amdgcn_mfma_f32_16x16x32_bf16(pa, vbf, accO[jn], 0, 0, 0);
        }
      }
      __builtin_amdgcn_s_setprio(0);

      if (pf) SINK_V(nxt, p0, p1, p2, p3);
      __syncthreads();
    }

    // ---- epilogue: accO[jn][rr] belongs to q-offset 4g+rr -> pull its l via shuffle
    #pragma unroll
    for (int rr = 0; rr < 4; rr++){
      float lr = __shfl(lrow, ((lane >> 4) << 2) + rr);
      float inv = 1.0f / lr;
      int qrow = qt*64 + (w << 4) + (g << 2) + rr;
      size_t rowbase = ((size_t)(b*T_ + qrow) << 10) + ((size_t)hh << 6);
      #pragma unroll
      for (int jn = 0; jn < 4; jn++){
        int d = (jn << 4) + l15;
        ctx[rowbase + d] = f2b(accO[jn][rr] * inv);
      }
    }
  }
#undef SINK_V
}

// ---------- launch ----------
extern "C" void kernel_launch(void* const* d_in, const int* in_sizes, int n_in,
                              void* d_out, int out_size, void* d_ws, size_t ws_size,
                              hipStream_t stream){
  (void)in_sizes; (void)n_in; (void)out_size; (void)ws_size;
  const float* x    = (const float*)d_in[0];
  const float* wq   = (const float*)d_in[1];
  const float* wk   = (const float*)d_in[2];
  const float* wv   = (const float*)d_in[3];
  const float* wo   = (const float*)d_in[4];
  const float* bo   = (const float*)d_in[5];
  const float* ln1s = (const float*)d_in[6];
  const float* ln1b = (const float*)d_in[7];
  const float* ln2s = (const float*)d_in[8];
  const float* ln2b = (const float*)d_in[9];
  const float* w1   = (const float*)d_in[10];
  const float* b1   = (const float*)d_in[11];
  const float* w2   = (const float*)d_in[12];
  const float* b2   = (const float*)d_in[13];
  float* out = (float*)d_out;

  char* p = (char*)d_ws;
  u16*  wqkvT = (u16*)p;  p += (size_t)3*D_*D_*2;
  u16*  woT   = (u16*)p;  p += (size_t)D_*D_*2;
  u16*  w1T   = (u16*)p;  p += (size_t)D_*DFF_*2;
  u16*  w2T   = (u16*)p;  p += (size_t)DFF_*D_*2;
  u16*  h     = (u16*)p;  p += (size_t)M_*D_*2;
  u16*  qb    = (u16*)p;  p += (size_t)M_*D_*2;
  u16*  kb    = (u16*)p;  p += (size_t)M_*D_*2;
  u16*  vb    = (u16*)p;  p += (size_t)M_*D_*2;
  u16*  ctx   = (u16*)p;  p += (size_t)M_*D_*2;
  float* x1   = (float*)p; p += (size_t)M_*D_*4;
  u16*  h2    = (u16*)p;  p += (size_t)M_*D_*2;
  u16*  ff1   = (u16*)p;  p += (size_t)M_*DFF_*2;
  (void)kb; (void)vb;
  float* part = (float*)h;   // [2][M][1024] fp32 recycled over dead h..vb region

  dim3 blk(256);
  wconv_all<<<3072, blk, 0, stream>>>(wq, wk, wv, wo, w1, w2, wqkvT, woT, w1T, w2T);
  ln_kernel<<<M_, blk, 0, stream>>>(x, ln1s, ln1b, h);
  gemm_k<1><<<dim3(24,32,1), blk, 0, stream>>>(h, wqkvT, nullptr, qb, M_, 3*D_, D_, D_);
  attn_k<<<dim3(16,32), blk, 0, stream>>>(qb, qb + (size_t)M_*D_, qb + 2*(size_t)M_*D_, ctx);
  gemm_k<0><<<dim3(8,32,2), blk, 0, stream>>>(ctx, woT, nullptr, part, M_, D_, D_/2, D_);
  reduce_ln<<<M_, blk, 0, stream>>>(part, bo, x, ln2s, ln2b, x1, h2);
  gemm_k<3><<<dim3(32,32,1), blk, 0, stream>>>(h2, w1T, b1, ff1, M_, DFF_, D_, D_);
  gemm_k<0><<<dim3(8,32,2), blk, 0, stream>>>(ff1, w2T, nullptr, part, M_, D_, DFF_/2, DFF_);
  reduce2<<<M_, blk, 0, stream>>>(part, b2, x1, out);
}

// Round 5
// 252.825 us; speedup vs baseline: 2.4487x; 1.1180x over previous
//
#include <hip/hip_runtime.h>
#include <hip/hip_bf16.h>
#include <stdint.h>

typedef unsigned short u16;
typedef __attribute__((ext_vector_type(8))) short s16x8;   // 8 bf16 (4 VGPRs) — MFMA A/B frag
typedef __attribute__((ext_vector_type(4))) float f32x4;   // MFMA C/D frag

#define B_   2
#define T_   2048
#define D_   1024
#define H_   16
#define HD_  64
#define DFF_ 4096
#define M_   (B_*T_)   // 4096

#define SC2F 0.18033688f   // (1/8) * log2(e) — folded into Q at QKV epilogue

// ---------- helpers ----------
__device__ __forceinline__ u16 f2b(float f){          // fp32 -> bf16, RNE
  uint32_t u = __float_as_uint(f);
  u += 0x7FFFu + ((u >> 16) & 1u);
  return (u16)(u >> 16);
}
__device__ __forceinline__ uint32_t pk2(float lo, float hi){  // 2xf32 -> packed 2xbf16
  uint32_t r;
  asm volatile("v_cvt_pk_bf16_f32 %0, %1, %2" : "=v"(r) : "v"(lo), "v"(hi));
  return r;
}

// async global->LDS, 16B per lane. LDS dest is wave-uniform-base + lane*16 (lane-linear).
__device__ __forceinline__ void gl_lds16(const void* g, void* l){
  __builtin_amdgcn_global_load_lds((const __attribute__((address_space(1))) void*)g,
                                   (__attribute__((address_space(3))) void*)l, 16, 0, 0);
}

#define WAITV4 asm volatile("s_waitcnt vmcnt(4)" ::: "memory")
#define WAITV0 asm volatile("s_waitcnt vmcnt(0)" ::: "memory")
#define BARRIER do{ asm volatile("":::"memory"); __builtin_amdgcn_s_barrier(); \
                    asm volatile("":::"memory"); }while(0)

// ---------- ALL weight conversions fp32 [K][N] -> bf16 [N][K], one launch ----------
__global__ __launch_bounds__(256) void wconv_all(const float* __restrict__ wq,
                                                 const float* __restrict__ wk,
                                                 const float* __restrict__ wv,
                                                 const float* __restrict__ wo,
                                                 const float* __restrict__ w1,
                                                 const float* __restrict__ w2,
                                                 u16* __restrict__ wqkvT, u16* __restrict__ woT,
                                                 u16* __restrict__ w1T,   u16* __restrict__ w2T){
  const int bid = blockIdx.x;
  const float* W; u16* Wt; int K, N, tk, tn;
  if (bid < 1024){
    const int which = bid >> 8, t = bid & 255; tk = t >> 4; tn = t & 15; K = 1024; N = 1024;
    W  = (which == 0) ? wq : (which == 1) ? wk : (which == 2) ? wv : wo;
    Wt = (which == 3) ? woT : wqkvT + (size_t)which * D_ * D_;
  } else if (bid < 2048){
    const int t = bid - 1024; tk = t >> 6; tn = t & 63; K = 1024; N = 4096; W = w1; Wt = w1T;
  } else {
    const int t = bid - 2048; tk = t >> 4; tn = t & 15; K = 4096; N = 1024; W = w2; Wt = w2T;
  }
  const int k0 = tk << 6, n0 = tn << 6;
  __shared__ u16 tile[64][68];
  const int tid = threadIdx.x;
  const int rr = tid >> 4, c4 = (tid & 15) << 2;
  #pragma unroll
  for (int rep = 0; rep < 4; rep++){
    int r = rr + (rep << 4);
    float4 v = *reinterpret_cast<const float4*>(W + (size_t)(k0 + r)*N + n0 + c4);
    tile[r][c4+0] = f2b(v.x); tile[r][c4+1] = f2b(v.y);
    tile[r][c4+2] = f2b(v.z); tile[r][c4+3] = f2b(v.w);
  }
  __syncthreads();
  const int rn = tid >> 2, kb = (tid & 3) << 4;
  u16 tmp[16];
  #pragma unroll
  for (int j = 0; j < 16; j++) tmp[j] = tile[kb + j][rn];
  ushort4* dst = reinterpret_cast<ushort4*>(Wt + (size_t)(n0 + rn)*K + k0 + kb);
  dst[0] = make_ushort4(tmp[0], tmp[1], tmp[2], tmp[3]);
  dst[1] = make_ushort4(tmp[4], tmp[5], tmp[6], tmp[7]);
  dst[2] = make_ushort4(tmp[8], tmp[9], tmp[10], tmp[11]);
  dst[3] = make_ushort4(tmp[12], tmp[13], tmp[14], tmp[15]);
}

// ---------- LayerNorm: fp32 [rows][1024] -> bf16 ----------
__global__ __launch_bounds__(256) void ln_kernel(const float* __restrict__ X,
                                                 const float* __restrict__ sc,
                                                 const float* __restrict__ sh,
                                                 u16* __restrict__ out){
  const int row = blockIdx.x;
  const int tid = threadIdx.x;
  float4 a = reinterpret_cast<const float4*>(X + ((size_t)row << 10))[tid];
  float s = a.x + a.y + a.z + a.w;
  float q = a.x*a.x + a.y*a.y + a.z*a.z + a.w*a.w;
  #pragma unroll
  for (int o = 32; o > 0; o >>= 1){ s += __shfl_xor(s, o); q += __shfl_xor(q, o); }
  __shared__ float red[8];
  const int w = tid >> 6;
  if ((tid & 63) == 0){ red[w] = s; red[4 + w] = q; }
  __syncthreads();
  float S = red[0] + red[1] + red[2] + red[3];
  float Q = red[4] + red[5] + red[6] + red[7];
  float mean = S * (1.0f/1024.0f);
  float var  = Q * (1.0f/1024.0f) - mean*mean;
  float inv = rsqrtf(var + 1e-5f);
  float4 gsc = reinterpret_cast<const float4*>(sc)[tid];
  float4 gsh = reinterpret_cast<const float4*>(sh)[tid];
  ushort4 o4;
  o4.x = f2b((a.x - mean)*inv*gsc.x + gsh.x);
  o4.y = f2b((a.y - mean)*inv*gsc.y + gsh.y);
  o4.z = f2b((a.z - mean)*inv*gsc.z + gsh.z);
  o4.w = f2b((a.w - mean)*inv*gsc.w + gsh.w);
  reinterpret_cast<ushort4*>(out + ((size_t)row << 10))[tid] = o4;
}

// ---------- split-K reduce (+bias+resid) -> fp32 out ----------
__global__ __launch_bounds__(256) void reduce2(const float* __restrict__ p,
                                               const float* __restrict__ bias,
                                               const float* __restrict__ resid,
                                               float* __restrict__ out){
  const size_t idx = ((size_t)blockIdx.x << 8) + threadIdx.x;
  float4 a = reinterpret_cast<const float4*>(p)[idx];
  float4 b = reinterpret_cast<const float4*>(p)[idx + (((size_t)M_*D_) >> 2)];
  float4 r = reinterpret_cast<const float4*>(resid)[idx];
  float4 bb = reinterpret_cast<const float4*>(bias)[threadIdx.x];
  float4 o;
  o.x = a.x + b.x + r.x + bb.x;
  o.y = a.y + b.y + r.y + bb.y;
  o.z = a.z + b.z + r.z + bb.z;
  o.w = a.w + b.w + r.w + bb.w;
  reinterpret_cast<float4*>(out)[idx] = o;
}

// ---------- fused: split-K reduce (+bo+resid) -> x1 fp32  AND  LayerNorm2 -> h2 bf16 ----------
__global__ __launch_bounds__(256) void reduce_ln(const float* __restrict__ p,
                                                 const float* __restrict__ bias,
                                                 const float* __restrict__ resid,
                                                 const float* __restrict__ sc,
                                                 const float* __restrict__ sh,
                                                 float* __restrict__ x1,
                                                 u16* __restrict__ h2){
  const int row = blockIdx.x;
  const int tid = threadIdx.x;
  const size_t idx = ((size_t)row << 8) + tid;
  float4 a  = reinterpret_cast<const float4*>(p)[idx];
  float4 b  = reinterpret_cast<const float4*>(p)[idx + (((size_t)M_*D_) >> 2)];
  float4 r  = reinterpret_cast<const float4*>(resid)[idx];
  float4 bb = reinterpret_cast<const float4*>(bias)[tid];
  float4 v;
  v.x = a.x + b.x + r.x + bb.x;
  v.y = a.y + b.y + r.y + bb.y;
  v.z = a.z + b.z + r.z + bb.z;
  v.w = a.w + b.w + r.w + bb.w;
  reinterpret_cast<float4*>(x1)[idx] = v;
  float s = v.x + v.y + v.z + v.w;
  float q = v.x*v.x + v.y*v.y + v.z*v.z + v.w*v.w;
  #pragma unroll
  for (int o = 32; o > 0; o >>= 1){ s += __shfl_xor(s, o); q += __shfl_xor(q, o); }
  __shared__ float red[8];
  const int w = tid >> 6;
  if ((tid & 63) == 0){ red[w] = s; red[4 + w] = q; }
  __syncthreads();
  float S = red[0] + red[1] + red[2] + red[3];
  float Q = red[4] + red[5] + red[6] + red[7];
  float mean = S * (1.0f/1024.0f);
  float var  = Q * (1.0f/1024.0f) - mean*mean;
  float inv = rsqrtf(var + 1e-5f);
  float4 gsc = reinterpret_cast<const float4*>(sc)[tid];
  float4 gsh = reinterpret_cast<const float4*>(sh)[tid];
  ushort4 o4;
  o4.x = f2b((v.x - mean)*inv*gsc.x + gsh.x);
  o4.y = f2b((v.y - mean)*inv*gsc.y + gsh.y);
  o4.z = f2b((v.z - mean)*inv*gsc.z + gsh.z);
  o4.w = f2b((v.w - mean)*inv*gsc.w + gsh.w);
  reinterpret_cast<ushort4*>(h2 + ((size_t)row << 10))[tid] = o4;
}

// ---------- bf16 GEMM: C[M,N] = A[M,K(lda)] @ Bt[N,K(lda)]^T ----------
// 128x128 tile, BK=32, 2-phase prefetch double-buffer with counted vmcnt (T3+T4 minimum),
// bijective XCD-chunk swizzle (T1). K/32 must be EVEN (true for all call sites).
// EPI 0: raw fp32 partial (split-K via gridDim.z)
// EPI 1: QKV scatter to [3][B][H][T][HD] bf16; Q part pre-scaled by SC2F
// EPI 3: gelu_tanh(+bias[n]) -> bf16 [M][N]
template<int EPI>
__global__ __launch_bounds__(256) void gemm_k(const u16* __restrict__ A, const u16* __restrict__ Bt,
                                              const float* __restrict__ bias,
                                              void* __restrict__ Cv, int M, int N, int K, int lda){
  __shared__ __align__(16) u16 As[2][128*32];
  __shared__ __align__(16) u16 Bs[2][128*32];
  const int tid = threadIdx.x;
  const int lane = tid & 63;
  const int w = tid >> 6;
  const int wr = w >> 1, wc = w & 1;
  const int g = lane >> 4, l15 = lane & 15;

  // bijective XCD swizzle: consecutive remapped ids share an XCD (nwg % 8 == 0 guaranteed)
  const int nx = gridDim.x, ny = gridDim.y;
  const int nwg = nx * ny * gridDim.z;
  const int flat = blockIdx.x + nx * (blockIdx.y + ny * blockIdx.z);
  const int nf = (flat & 7) * (nwg >> 3) + (flat >> 3);
  const int tn = nf % nx;
  const int rest = nf / nx;
  const int tm = rest % ny;
  const int kz = rest / ny;
  const int tn0 = tn << 7;
  const int tm0 = tm << 7;
  const u16* Az = A  + (size_t)kz * K;
  const u16* Bz = Bt + (size_t)kz * K;

  f32x4 acc[4][4];
  #pragma unroll
  for (int i = 0; i < 4; i++)
    #pragma unroll
    for (int j = 0; j < 4; j++) acc[i][j] = (f32x4){0.f,0.f,0.f,0.f};

  const int ch0 = tid, ch1 = 256 + tid;
  const int r0 = ch0 >> 2, c0 = (((ch0 & 3) ^ ((r0 >> 1) & 3)) << 3);
  const int r1 = ch1 >> 2, c1 = (((ch1 & 3) ^ ((r1 >> 1) & 3)) << 3);
  const u16* A0 = Az + (size_t)(tm0 + r0)*lda + c0;
  const u16* A1 = Az + (size_t)(tm0 + r1)*lda + c1;
  const u16* B0 = Bz + (size_t)(tn0 + r0)*lda + c0;
  const u16* B1 = Bz + (size_t)(tn0 + r1)*lda + c1;

#define GSTAGE(BUF, TI) do {                         \
    const int off_ = (TI) << 5;                      \
    gl_lds16(A0 + off_, As[BUF] + ch0*8);            \
    gl_lds16(A1 + off_, As[BUF] + ch1*8);            \
    gl_lds16(B0 + off_, Bs[BUF] + ch0*8);            \
    gl_lds16(B1 + off_, Bs[BUF] + ch1*8);            \
  } while(0)

#define GCOMP(BUF) do {                                                                   \
    s16x8 af[4], bf[4];                                                                   \
    _Pragma("unroll")                                                                     \
    for (int i = 0; i < 4; i++){                                                          \
      int ra = (wr << 6) + (i << 4) + l15;                                                \
      af[i] = *reinterpret_cast<const s16x8*>(As[BUF] + ra*32 + ((g ^ ((ra >> 1) & 3)) << 3)); \
    }                                                                                     \
    _Pragma("unroll")                                                                     \
    for (int j = 0; j < 4; j++){                                                          \
      int rb = (wc << 6) + (j << 4) + l15;                                                \
      bf[j] = *reinterpret_cast<const s16x8*>(Bs[BUF] + rb*32 + ((g ^ ((rb >> 1) & 3)) << 3)); \
    }                                                                                     \
    _Pragma("unroll")                                                                     \
    for (int i = 0; i < 4; i++)                                                           \
      _Pragma("unroll")                                                                   \
      for (int j = 0; j < 4; j++)                                                         \
        acc[i][j] = __builtin_amdgcn_mfma_f32_16x16x32_bf16(af[i], bf[j], acc[i][j], 0, 0, 0); \
  } while(0)

  const int NT = K >> 5;           // even at every call site
  GSTAGE(0, 0);
  for (int t = 0; t < NT; t += 2){
    if (t + 1 < NT) { GSTAGE(1, t + 1); WAITV4; } else { WAITV0; }
    BARRIER;                        // buf0 ready block-wide; buf1 loads in flight
    GCOMP(0);
    BARRIER;                        // all reads of buf0 done -> next stage may overwrite
    if (t + 2 < NT) { GSTAGE(0, t + 2); WAITV4; } else { WAITV0; }
    BARRIER;
    GCOMP(1);
    BARRIER;
  }
#undef GSTAGE
#undef GCOMP

  #pragma unroll
  for (int i = 0; i < 4; i++){
    const int mb = tm0 + (wr << 6) + (i << 4) + (g << 2);
    #pragma unroll
    for (int j = 0; j < 4; j++){
      const int n = tn0 + (wc << 6) + (j << 4) + l15;
      #pragma unroll
      for (int rr = 0; rr < 4; rr++){
        const int m = mb + rr;
        float v = acc[i][j][rr];
        if constexpr (EPI == 0){
          ((float*)Cv)[(size_t)kz*((size_t)M*N) + (size_t)m*N + n] = v;
        } else if constexpr (EPI == 1){
          const int sel = n >> 10, nn = n & 1023;
          const int hh = nn >> 6, d = nn & 63;
          if (sel == 0) v *= SC2F;                     // pre-scale Q for exp2-domain softmax
          ((u16*)Cv)[(size_t)sel*((size_t)M_*D_) +
                     ((((size_t)(m >> 11)*H_ + hh)*T_ + (m & 2047)) << 6) + d] = f2b(v);
        } else {
          float u = v + bias[n];
          float t2 = 0.7978845608f*(u + 0.044715f*u*u*u);
          float e = __expf(2.0f*t2);
          float th = 1.0f - 2.0f/(e + 1.0f);
          ((u16*)Cv)[(size_t)m*N + n] = f2b(0.5f*u*(1.0f + th));
        }
      }
    }
  }
}

// ---------- causal flash attention, v5 ----------
// XCD remap: all 16 pair-blocks of one head land on one XCD (4 heads/XCD -> 2MB K/V in L2).
// Swapped QK^T (lane-local softmax), T13 defer-rescale, packed P-stores (cvt_pk_bf16 + uint2).
__global__ __launch_bounds__(256) void attn_k(const u16* __restrict__ Qg, const u16* __restrict__ Kg,
                                              const u16* __restrict__ Vg, u16* __restrict__ ctx){
  // flat in [0,512): xcd = flat&7; bh = (j&3)*8 + xcd; pair = j>>2  (bijective)
  const int flat = blockIdx.x + (blockIdx.y << 4);
  const int xcd = flat & 7, j_ = flat >> 3;
  const int bh  = ((j_ & 3) << 3) + xcd;
  const int pr_ = j_ >> 2;
  const int tid = threadIdx.x;
  const int lane = tid & 63;
  const int w = tid >> 6;
  const int g = lane >> 4, l15 = lane & 15;

  __shared__ __align__(16) u16 Qs[64*64];
  __shared__ __align__(16) u16 Ks[2][64*64];
  __shared__ __align__(16) u16 Vt[2][64*64];
  __shared__ __align__(16) u16 Pl[4][16*64];

  const size_t hb = (size_t)bh * ((size_t)T_*HD_);
  const u16* Qh = Qg + hb;
  const u16* Kh = Kg + hb;
  const u16* Vh = Vg + hb;
  const int b = bh >> 4, hh = bh & 15;

  const int s_r0 = tid >> 3,        s_c0 = (((tid & 7) ^ (s_r0 & 7)) << 3);
  const int s_r1 = (256+tid) >> 3,  s_c1 = ((((256+tid) & 7) ^ (s_r1 & 7)) << 3);
  const int v_kr = tid >> 2, v_d0 = (tid & 3) << 4;

#define SINK_V(buf, q0, q1, q2, q3) do {                                          \
    u16 vv[16] = {q0.x,q0.y,q0.z,q0.w, q1.x,q1.y,q1.z,q1.w,                       \
                  q2.x,q2.y,q2.z,q2.w, q3.x,q3.y,q3.z,q3.w};                      \
    _Pragma("unroll")                                                             \
    for (int j = 0; j < 16; j++){                                                 \
      int d = v_d0 + j;                                                           \
      Vt[buf][d*64 + ((((v_kr >> 3) ^ (d & 7) ^ ((d >> 4) << 1)) & 7) << 3)       \
              + (v_kr & 7)] = vv[j];                                              \
    }                                                                             \
  } while (0)

  for (int ph = 0; ph < 2; ++ph){
    const int qt = ph ? (31 - pr_) : pr_;

    gl_lds16(Qh + (size_t)(qt*64 + s_r0)*HD_ + s_c0, Qs + tid*8);
    gl_lds16(Qh + (size_t)(qt*64 + s_r1)*HD_ + s_c1, Qs + (256+tid)*8);
    gl_lds16(Kh + (size_t)(s_r0)*HD_ + s_c0, Ks[0] + tid*8);
    gl_lds16(Kh + (size_t)(s_r1)*HD_ + s_c1, Ks[0] + (256+tid)*8);
    {
      const u16* vs = Vh + (size_t)v_kr*HD_ + v_d0;
      ushort4 a0 = *(const ushort4*)(vs + 0);
      ushort4 a1 = *(const ushort4*)(vs + 4);
      ushort4 a2 = *(const ushort4*)(vs + 8);
      ushort4 a3 = *(const ushort4*)(vs + 12);
      SINK_V(0, a0, a1, a2, a3);
    }
    __syncthreads();

    s16x8 qa[2];
    #pragma unroll
    for (int kk = 0; kk < 2; kk++){
      int ra = (w << 4) + l15;
      int slot = (kk << 2) + g;
      qa[kk] = *reinterpret_cast<const s16x8*>(Qs + ra*64 + ((slot ^ (ra & 7)) << 3));
    }

    f32x4 accO[4];
    #pragma unroll
    for (int j = 0; j < 4; j++) accO[j] = (f32x4){0.f,0.f,0.f,0.f};
    float mrow = -1e30f, lrow = 0.f;            // scalars: this thread's q = 16w + l15
    const int qlt = (w << 4) + l15;

    for (int kt = 0; kt <= qt; ++kt){
      const int cur = kt & 1, nxt = cur ^ 1;
      const bool pf = (kt < qt);

      ushort4 p0, p1, p2, p3;
      if (pf){
        gl_lds16(Kh + (size_t)((kt+1)*64 + s_r0)*HD_ + s_c0, Ks[nxt] + tid*8);
        gl_lds16(Kh + (size_t)((kt+1)*64 + s_r1)*HD_ + s_c1, Ks[nxt] + (256+tid)*8);
        const u16* vs = Vh + (size_t)((kt+1)*64 + v_kr)*HD_ + v_d0;
        p0 = *(const ushort4*)(vs + 0);
        p1 = *(const ushort4*)(vs + 4);
        p2 = *(const ushort4*)(vs + 8);
        p3 = *(const ushort4*)(vs + 12);
      }

      // ---- S^T = K Q^T (swapped operands)
      f32x4 accS[4];
      #pragma unroll
      for (int j = 0; j < 4; j++) accS[j] = (f32x4){0.f,0.f,0.f,0.f};
      __builtin_amdgcn_s_setprio(1);
      #pragma unroll
      for (int jn = 0; jn < 4; jn++){
        #pragma unroll
        for (int kk = 0; kk < 2; kk++){
          int rb = (jn << 4) + l15;
          int slot = (kk << 2) + g;
          s16x8 kf = *reinterpret_cast<const s16x8*>(Ks[cur] + rb*64 + ((slot ^ (rb & 7)) << 3));
          accS[jn] = __builtin_amdgcn_mfma_f32_16x16x32_bf16(kf, qa[kk], accS[jn], 0, 0, 0);
        }
      }
      __builtin_amdgcn_s_setprio(0);

      // ---- mask (diagonal tile); values already in log2 domain (Q pre-scaled)
      float sv[4][4];
      #pragma unroll
      for (int jn = 0; jn < 4; jn++)
        #pragma unroll
        for (int rr = 0; rr < 4; rr++){
          float xv = accS[jn][rr];
          if (kt == qt){
            int kl = (jn << 4) + (g << 2) + rr;
            if (kl > qlt) xv = -1e30f;
          }
          sv[jn][rr] = xv;
        }

      // ---- row max: register chain + 2 shuffles
      float rmax = sv[0][0];
      #pragma unroll
      for (int jn = 0; jn < 4; jn++)
        #pragma unroll
        for (int rr = 0; rr < 4; rr++) rmax = fmaxf(rmax, sv[jn][rr]);
      rmax = fmaxf(rmax, __shfl_xor(rmax, 16));
      rmax = fmaxf(rmax, __shfl_xor(rmax, 32));

      // ---- T13: rescale only when the running max grew by >8 (log2 domain)
      if (__any(rmax > mrow + 8.0f)){
        float mn = fmaxf(mrow, rmax);
        float sf = exp2f(mrow - mn);
        mrow = mn;
        lrow *= sf;
        #pragma unroll
        for (int rr = 0; rr < 4; rr++){
          float sfr = __shfl(sf, ((lane >> 4) << 2) + rr);
          #pragma unroll
          for (int jn = 0; jn < 4; jn++) accO[jn][rr] *= sfr;
        }
      }

      // ---- P = exp2(S^T - m), packed store (2x cvt_pk + one uint2 per jn)
      float tsum = 0.f;
      #pragma unroll
      for (int jn = 0; jn < 4; jn++){
        float pv0 = exp2f(sv[jn][0] - mrow);
        float pv1 = exp2f(sv[jn][1] - mrow);
        float pv2 = exp2f(sv[jn][2] - mrow);
        float pv3 = exp2f(sv[jn][3] - mrow);
        tsum += (pv0 + pv1) + (pv2 + pv3);
        int slot = (jn << 1) | (g >> 1);
        int base = l15*64 + (((slot ^ (l15 & 7)) & 7) << 3) + ((g & 1) << 2);
        uint2 pkd = make_uint2(pk2(pv0, pv1), pk2(pv2, pv3));
        *reinterpret_cast<uint2*>(&Pl[w][base]) = pkd;
      }
      tsum += __shfl_xor(tsum, 16);
      tsum += __shfl_xor(tsum, 32);
      lrow += tsum;

      // ---- O += P V
      __builtin_amdgcn_s_setprio(1);
      #pragma unroll
      for (int kk = 0; kk < 2; kk++){
        int slot = (kk << 2) + g;
        s16x8 pa = *reinterpret_cast<const s16x8*>(
            &Pl[w][l15*64 + (((slot ^ (l15 & 7)) & 7) << 3)]);
        #pragma unroll
        for (int jn = 0; jn < 4; jn++){
          int vd = (jn << 4) + l15;
          s16x8 vbf = *reinterpret_cast<const s16x8*>(
              Vt[cur] + vd*64 + (((slot ^ (vd & 7) ^ ((vd >> 4) << 1)) & 7) << 3));
          accO[jn] = __builtin_amdgcn_mfma_f32_16x16x32_bf16(pa, vbf, accO[jn], 0, 0, 0);
        }
      }
      __builtin_amdgcn_s_setprio(0);

      if (pf) SINK_V(nxt, p0, p1, p2, p3);
      __syncthreads();
    }

    // ---- epilogue
    #pragma unroll
    for (int rr = 0; rr < 4; rr++){
      float lr = __shfl(lrow, ((lane >> 4) << 2) + rr);
      float inv = 1.0f / lr;
      int qrow = qt*64 + (w << 4) + (g << 2) + rr;
      size_t rowbase = ((size_t)(b*T_ + qrow) << 10) + ((size_t)hh << 6);
      #pragma unroll
      for (int jn = 0; jn < 4; jn++){
        int d = (jn << 4) + l15;
        ctx[rowbase + d] = f2b(accO[jn][rr] * inv);
      }
    }
  }
#undef SINK_V
}

// ---------- launch ----------
extern "C" void kernel_launch(void* const* d_in, const int* in_sizes, int n_in,
                              void* d_out, int out_size, void* d_ws, size_t ws_size,
                              hipStream_t stream){
  (void)in_sizes; (void)n_in; (void)out_size; (void)ws_size;
  const float* x    = (const float*)d_in[0];
  const float* wq   = (const float*)d_in[1];
  const float* wk   = (const float*)d_in[2];
  const float* wv   = (const float*)d_in[3];
  const float* wo   = (const float*)d_in[4];
  const float* bo   = (const float*)d_in[5];
  const float* ln1s = (const float*)d_in[6];
  const float* ln1b = (const float*)d_in[7];
  const float* ln2s = (const float*)d_in[8];
  const float* ln2b = (const float*)d_in[9];
  const float* w1   = (const float*)d_in[10];
  const float* b1   = (const float*)d_in[11];
  const float* w2   = (const float*)d_in[12];
  const float* b2   = (const float*)d_in[13];
  float* out = (float*)d_out;

  char* p = (char*)d_ws;
  u16*  wqkvT = (u16*)p;  p += (size_t)3*D_*D_*2;
  u16*  woT   = (u16*)p;  p += (size_t)D_*D_*2;
  u16*  w1T   = (u16*)p;  p += (size_t)D_*DFF_*2;
  u16*  w2T   = (u16*)p;  p += (size_t)DFF_*D_*2;
  u16*  h     = (u16*)p;  p += (size_t)M_*D_*2;
  u16*  qb    = (u16*)p;  p += (size_t)M_*D_*2;
  u16*  kb    = (u16*)p;  p += (size_t)M_*D_*2;
  u16*  vb    = (u16*)p;  p += (size_t)M_*D_*2;
  u16*  ctx   = (u16*)p;  p += (size_t)M_*D_*2;
  float* x1   = (float*)p; p += (size_t)M_*D_*4;
  u16*  h2    = (u16*)p;  p += (size_t)M_*D_*2;
  u16*  ff1   = (u16*)p;  p += (size_t)M_*DFF_*2;
  (void)kb; (void)vb;
  float* part = (float*)h;   // [2][M][1024] fp32 recycled over dead h..vb region

  dim3 blk(256);
  wconv_all<<<3072, blk, 0, stream>>>(wq, wk, wv, wo, w1, w2, wqkvT, woT, w1T, w2T);
  ln_kernel<<<M_, blk, 0, stream>>>(x, ln1s, ln1b, h);
  gemm_k<1><<<dim3(24,32,1), blk, 0, stream>>>(h, wqkvT, nullptr, qb, M_, 3*D_, D_, D_);
  attn_k<<<dim3(16,32), blk, 0, stream>>>(qb, qb + (size_t)M_*D_, qb + 2*(size_t)M_*D_, ctx);
  gemm_k<0><<<dim3(8,32,2), blk, 0, stream>>>(ctx, woT, nullptr, part, M_, D_, D_/2, D_);
  reduce_ln<<<M_, blk, 0, stream>>>(part, bo, x, ln2s, ln2b, x1, h2);
  gemm_k<3><<<dim3(32,32,1), blk, 0, stream>>>(h2, w1T, b1, ff1, M_, DFF_, D_, D_);
  gemm_k<0><<<dim3(8,32,2), blk, 0, stream>>>(ff1, w2T, nullptr, part, M_, D_, DFF_/2, DFF_);
  reduce2<<<M_, blk, 0, stream>>>(part, b2, x1, out);
}

// Round 6
// 239.512 us; speedup vs baseline: 2.5848x; 1.0556x over previous
//
#include <hip/hip_runtime.h>
#include <hip/hip_bf16.h>
#include <stdint.h>

typedef unsigned short u16;
typedef __attribute__((ext_vector_type(8))) short s16x8;   // 8 bf16 (4 VGPRs) — MFMA A/B frag
typedef __attribute__((ext_vector_type(4))) float f32x4;   // MFMA C/D frag

#define B_   2
#define T_   2048
#define D_   1024
#define H_   16
#define HD_  64
#define DFF_ 4096
#define M_   (B_*T_)   // 4096

#define SC2F 0.18033688f   // (1/8) * log2(e) — folded into Q at QKV epilogue

// ---------- helpers ----------
__device__ __forceinline__ u16 f2b(float f){          // fp32 -> bf16, RNE
  uint32_t u = __float_as_uint(f);
  u += 0x7FFFu + ((u >> 16) & 1u);
  return (u16)(u >> 16);
}
__device__ __forceinline__ uint32_t pk2(float lo, float hi){  // 2xf32 -> packed 2xbf16
  uint32_t r;
  asm volatile("v_cvt_pk_bf16_f32 %0, %1, %2" : "=v"(r) : "v"(lo), "v"(hi));
  return r;
}

// async global->LDS, 16B per lane. LDS dest is wave-uniform-base + lane*16 (lane-linear).
__device__ __forceinline__ void gl_lds16(const void* g, void* l){
  __builtin_amdgcn_global_load_lds((const __attribute__((address_space(1))) void*)g,
                                   (__attribute__((address_space(3))) void*)l, 16, 0, 0);
}

template<int N> __device__ __forceinline__ void waitvm(){
  if constexpr (N == 0)      asm volatile("s_waitcnt vmcnt(0)" ::: "memory");
  else if constexpr (N == 2) asm volatile("s_waitcnt vmcnt(2)" ::: "memory");
  else                       asm volatile("s_waitcnt vmcnt(4)" ::: "memory");
}

// ---------- ALL weight conversions fp32 [K][N] -> bf16 [N][K], one launch ----------
__global__ __launch_bounds__(256) void wconv_all(const float* __restrict__ wq,
                                                 const float* __restrict__ wk,
                                                 const float* __restrict__ wv,
                                                 const float* __restrict__ wo,
                                                 const float* __restrict__ w1,
                                                 const float* __restrict__ w2,
                                                 u16* __restrict__ wqkvT, u16* __restrict__ woT,
                                                 u16* __restrict__ w1T,   u16* __restrict__ w2T){
  const int bid = blockIdx.x;
  const float* W; u16* Wt; int K, N, tk, tn;
  if (bid < 1024){
    const int which = bid >> 8, t = bid & 255; tk = t >> 4; tn = t & 15; K = 1024; N = 1024;
    W  = (which == 0) ? wq : (which == 1) ? wk : (which == 2) ? wv : wo;
    Wt = (which == 3) ? woT : wqkvT + (size_t)which * D_ * D_;
  } else if (bid < 2048){
    const int t = bid - 1024; tk = t >> 6; tn = t & 63; K = 1024; N = 4096; W = w1; Wt = w1T;
  } else {
    const int t = bid - 2048; tk = t >> 4; tn = t & 15; K = 4096; N = 1024; W = w2; Wt = w2T;
  }
  const int k0 = tk << 6, n0 = tn << 6;
  __shared__ u16 tile[64][68];
  const int tid = threadIdx.x;
  const int rr = tid >> 4, c4 = (tid & 15) << 2;
  #pragma unroll
  for (int rep = 0; rep < 4; rep++){
    int r = rr + (rep << 4);
    float4 v = *reinterpret_cast<const float4*>(W + (size_t)(k0 + r)*N + n0 + c4);
    tile[r][c4+0] = f2b(v.x); tile[r][c4+1] = f2b(v.y);
    tile[r][c4+2] = f2b(v.z); tile[r][c4+3] = f2b(v.w);
  }
  __syncthreads();
  const int rn = tid >> 2, kb = (tid & 3) << 4;
  u16 tmp[16];
  #pragma unroll
  for (int j = 0; j < 16; j++) tmp[j] = tile[kb + j][rn];
  ushort4* dst = reinterpret_cast<ushort4*>(Wt + (size_t)(n0 + rn)*K + k0 + kb);
  dst[0] = make_ushort4(tmp[0], tmp[1], tmp[2], tmp[3]);
  dst[1] = make_ushort4(tmp[4], tmp[5], tmp[6], tmp[7]);
  dst[2] = make_ushort4(tmp[8], tmp[9], tmp[10], tmp[11]);
  dst[3] = make_ushort4(tmp[12], tmp[13], tmp[14], tmp[15]);
}

// ---------- LayerNorm: fp32 [rows][1024] -> bf16 ----------
__global__ __launch_bounds__(256) void ln_kernel(const float* __restrict__ X,
                                                 const float* __restrict__ sc,
                                                 const float* __restrict__ sh,
                                                 u16* __restrict__ out){
  const int row = blockIdx.x;
  const int tid = threadIdx.x;
  float4 a = reinterpret_cast<const float4*>(X + ((size_t)row << 10))[tid];
  float s = a.x + a.y + a.z + a.w;
  float q = a.x*a.x + a.y*a.y + a.z*a.z + a.w*a.w;
  #pragma unroll
  for (int o = 32; o > 0; o >>= 1){ s += __shfl_xor(s, o); q += __shfl_xor(q, o); }
  __shared__ float red[8];
  const int w = tid >> 6;
  if ((tid & 63) == 0){ red[w] = s; red[4 + w] = q; }
  __syncthreads();
  float S = red[0] + red[1] + red[2] + red[3];
  float Q = red[4] + red[5] + red[6] + red[7];
  float mean = S * (1.0f/1024.0f);
  float var  = Q * (1.0f/1024.0f) - mean*mean;
  float inv = rsqrtf(var + 1e-5f);
  float4 gsc = reinterpret_cast<const float4*>(sc)[tid];
  float4 gsh = reinterpret_cast<const float4*>(sh)[tid];
  ushort4 o4;
  o4.x = f2b((a.x - mean)*inv*gsc.x + gsh.x);
  o4.y = f2b((a.y - mean)*inv*gsc.y + gsh.y);
  o4.z = f2b((a.z - mean)*inv*gsc.z + gsh.z);
  o4.w = f2b((a.w - mean)*inv*gsc.w + gsh.w);
  reinterpret_cast<ushort4*>(out + ((size_t)row << 10))[tid] = o4;
}

// ---------- split-K reduce (+bias+resid) -> fp32 out ----------
__global__ __launch_bounds__(256) void reduce2(const float* __restrict__ p,
                                               const float* __restrict__ bias,
                                               const float* __restrict__ resid,
                                               float* __restrict__ out){
  const size_t idx = ((size_t)blockIdx.x << 8) + threadIdx.x;
  float4 a = reinterpret_cast<const float4*>(p)[idx];
  float4 b = reinterpret_cast<const float4*>(p)[idx + (((size_t)M_*D_) >> 2)];
  float4 r = reinterpret_cast<const float4*>(resid)[idx];
  float4 bb = reinterpret_cast<const float4*>(bias)[threadIdx.x];
  float4 o;
  o.x = a.x + b.x + r.x + bb.x;
  o.y = a.y + b.y + r.y + bb.y;
  o.z = a.z + b.z + r.z + bb.z;
  o.w = a.w + b.w + r.w + bb.w;
  reinterpret_cast<float4*>(out)[idx] = o;
}

// ---------- fused: split-K reduce (+bo+resid) -> x1 fp32  AND  LayerNorm2 -> h2 bf16 ----------
__global__ __launch_bounds__(256) void reduce_ln(const float* __restrict__ p,
                                                 const float* __restrict__ bias,
                                                 const float* __restrict__ resid,
                                                 const float* __restrict__ sc,
                                                 const float* __restrict__ sh,
                                                 float* __restrict__ x1,
                                                 u16* __restrict__ h2){
  const int row = blockIdx.x;
  const int tid = threadIdx.x;
  const size_t idx = ((size_t)row << 8) + tid;
  float4 a  = reinterpret_cast<const float4*>(p)[idx];
  float4 b  = reinterpret_cast<const float4*>(p)[idx + (((size_t)M_*D_) >> 2)];
  float4 r  = reinterpret_cast<const float4*>(resid)[idx];
  float4 bb = reinterpret_cast<const float4*>(bias)[tid];
  float4 v;
  v.x = a.x + b.x + r.x + bb.x;
  v.y = a.y + b.y + r.y + bb.y;
  v.z = a.z + b.z + r.z + bb.z;
  v.w = a.w + b.w + r.w + bb.w;
  reinterpret_cast<float4*>(x1)[idx] = v;
  float s = v.x + v.y + v.z + v.w;
  float q = v.x*v.x + v.y*v.y + v.z*v.z + v.w*v.w;
  #pragma unroll
  for (int o = 32; o > 0; o >>= 1){ s += __shfl_xor(s, o); q += __shfl_xor(q, o); }
  __shared__ float red[8];
  const int w = tid >> 6;
  if ((tid & 63) == 0){ red[w] = s; red[4 + w] = q; }
  __syncthreads();
  float S = red[0] + red[1] + red[2] + red[3];
  float Q = red[4] + red[5] + red[6] + red[7];
  float mean = S * (1.0f/1024.0f);
  float var  = Q * (1.0f/1024.0f) - mean*mean;
  float inv = rsqrtf(var + 1e-5f);
  float4 gsc = reinterpret_cast<const float4*>(sc)[tid];
  float4 gsh = reinterpret_cast<const float4*>(sh)[tid];
  ushort4 o4;
  o4.x = f2b((v.x - mean)*inv*gsc.x + gsh.x);
  o4.y = f2b((v.y - mean)*inv*gsc.y + gsh.y);
  o4.z = f2b((v.z - mean)*inv*gsc.z + gsh.z);
  o4.w = f2b((v.w - mean)*inv*gsc.w + gsh.w);
  reinterpret_cast<ushort4*>(h2 + ((size_t)row << 10))[tid] = o4;
}

// ---------- 8-phase 256-wide bf16 GEMM (HK-template port, plain HIP) ----------
// C[M, N] = A[M,K(lda)] @ Bt[N,K(lda)]^T. BM=256, BN=NF*64 (NF=4 -> 256, NF=2 -> 128), BK=64.
// 512 threads = 8 waves (2M x 4N); per-wave out 128 x NF*16. LDS: A 2dbufx2half [128][64],
// B 2dbufx2half [NF*32][64]; slot^=(row&7) XOR swizzle (inverse-permuted global source).
// Counted vmcnt(NF) at phases 4/8 only (never 0 in steady state). K/64 must be EVEN.
// EPI 0: fp32 partial (split-K via gridDim.z)  EPI 1: QKV scatter (Q pre-scaled SC2F)
// EPI 3: gelu_tanh(+bias) -> bf16
template<int EPI, int NF>
__global__ __launch_bounds__(512, 2) void gemm8(const u16* __restrict__ A, const u16* __restrict__ Bt,
                                                const float* __restrict__ bias,
                                                void* __restrict__ Cv, int M, int N, int K, int lda){
  constexpr int BROWS = NF * 32;            // rows per B half-tile
  __shared__ __align__(16) u16 LA[2][2][128*64];
  __shared__ __align__(16) u16 LB[2][2][BROWS*64];
  const int tid = threadIdx.x;
  const int lane = tid & 63;
  const int w = tid >> 6;
  const int wm = w >> 2, wn = w & 3;
  const int g = lane >> 4, l15 = lane & 15;
  const int bnb = (wn & 1) * (NF * 16);     // B local row base within half (wn>>1)

  // bijective XCD-chunk swizzle (nwg % 8 == 0 at every call site)
  const int nx = gridDim.x, ny = gridDim.y;
  const int nwg = nx * ny * gridDim.z;
  const int flat = blockIdx.x + nx * (blockIdx.y + ny * blockIdx.z);
  const int nfid = (flat & 7) * (nwg >> 3) + (flat >> 3);
  const int tn = nfid % nx;
  const int rest = nfid / nx;
  const int tm = rest % ny;
  const int kz = rest / ny;
  const int tn0 = tn * (NF * 64);
  const int tm0 = tm << 8;
  const u16* Az = A  + (size_t)kz * K;
  const u16* Bz = Bt + (size_t)kz * K;

  // staging source coords (thread-constant; inverse of slot^=(row&7))
  const int arow0 = tid >> 3,         asl0 = (((tid) & 7) ^ (arow0 & 7)) << 3;
  const int arow1 = (tid + 512) >> 3, asl1 = (((tid + 512) & 7) ^ (arow1 & 7)) << 3;

  f32x4 acc[8][NF];
  #pragma unroll
  for (int i = 0; i < 8; i++)
    #pragma unroll
    for (int j = 0; j < NF; j++) acc[i][j] = (f32x4){0.f,0.f,0.f,0.f};
  s16x8 bf[NF][2];

#define STG_A(db, h, tt) do{                                                        \
    gl_lds16(Az + (size_t)(tm0 + (h)*128 + arow0)*lda + ((tt) << 6) + asl0,         \
             &LA[db][h][tid*8]);                                                    \
    gl_lds16(Az + (size_t)(tm0 + (h)*128 + arow1)*lda + ((tt) << 6) + asl1,         \
             &LA[db][h][(tid + 512)*8]);                                            \
  }while(0)
#define STG_B(db, h, tt) do{                                                        \
    gl_lds16(Bz + (size_t)(tn0 + (h)*BROWS + arow0)*lda + ((tt) << 6) + asl0,       \
             &LB[db][h][tid*8]);                                                    \
    if constexpr (NF == 4){                                                         \
      gl_lds16(Bz + (size_t)(tn0 + (h)*BROWS + arow1)*lda + ((tt) << 6) + asl1,     \
               &LB[db][h][(tid + 512)*8]);                                          \
    }                                                                               \
  }while(0)
#define LDAF(db, mf, kk) (*reinterpret_cast<const s16x8*>(                          \
    &LA[db][wm][((mf)*16 + l15)*64 + ((((kk)*4 + g) ^ (l15 & 7)) << 3)]))
#define LDBF(db, nf, kk) (*reinterpret_cast<const s16x8*>(                          \
    &LB[db][wn >> 1][(bnb + (nf)*16 + l15)*64 + ((((kk)*4 + g) ^ (l15 & 7)) << 3)]))
#define BLOAD(db) do{ _Pragma("unroll")                                             \
    for (int nf = 0; nf < NF; nf++){ bf[nf][0] = LDBF(db, nf, 0);                   \
                                     bf[nf][1] = LDBF(db, nf, 1); } }while(0)
#define PH(db, MFA, MFB, STG, WV) do{                                               \
    s16x8 a00 = LDAF(db, MFA, 0), a01 = LDAF(db, MFA, 1);                           \
    s16x8 a10 = LDAF(db, MFB, 0), a11 = LDAF(db, MFB, 1);                           \
    STG;                                                                            \
    WV;                                                                             \
    __builtin_amdgcn_s_barrier();                                                   \
    __builtin_amdgcn_s_setprio(1);                                                  \
    _Pragma("unroll")                                                               \
    for (int nf = 0; nf < NF; nf++){                                                \
      acc[MFA][nf] = __builtin_amdgcn_mfma_f32_16x16x32_bf16(a00, bf[nf][0], acc[MFA][nf], 0,0,0); \
      acc[MFA][nf] = __builtin_amdgcn_mfma_f32_16x16x32_bf16(a01, bf[nf][1], acc[MFA][nf], 0,0,0); \
      acc[MFB][nf] = __builtin_amdgcn_mfma_f32_16x16x32_bf16(a10, bf[nf][0], acc[MFB][nf], 0,0,0); \
      acc[MFB][nf] = __builtin_amdgcn_mfma_f32_16x16x32_bf16(a11, bf[nf][1], acc[MFB][nf], 0,0,0); \
    }                                                                               \
    __builtin_amdgcn_s_setprio(0);                                                  \
    __builtin_amdgcn_s_barrier();                                                   \
  }while(0)

  const int NT = K >> 6;                     // even at every call site
  // prologue: tile0 fully + B halves of tile1 (12 / 8 loads per thread), wait tile0
  STG_B(0, 0, 0); STG_B(0, 1, 0); STG_A(0, 0, 0); STG_A(0, 1, 0);
  STG_B(1, 0, 1); STG_B(1, 1, 1);
  waitvm<NF>();
  __builtin_amdgcn_s_barrier();

  for (int t = 0; t < NT; t += 2){
    const bool last = (t + 2 >= NT);
    BLOAD(0);
    PH(0, 0, 1, STG_A(1, 0, t + 1), );
    PH(0, 2, 3, STG_A(1, 1, t + 1), );
    PH(0, 4, 5, if (!last) STG_B(0, 0, t + 2), );
    PH(0, 6, 7, if (!last) STG_B(0, 1, t + 2),
                if (last) waitvm<0>(); else waitvm<NF>(););
    BLOAD(1);
    PH(1, 0, 1, if (!last) STG_A(0, 0, t + 2), );
    PH(1, 2, 3, if (!last) STG_A(0, 1, t + 2), );
    PH(1, 4, 5, if (!last) STG_B(1, 0, t + 3), );
    PH(1, 6, 7, if (!last) STG_B(1, 1, t + 3),
                if (last) waitvm<0>(); else waitvm<NF>(););
  }
#undef STG_A
#undef STG_B
#undef LDAF
#undef LDBF
#undef BLOAD
#undef PH

  #pragma unroll
  for (int mf = 0; mf < 8; mf++){
    const int mb = tm0 + wm*128 + mf*16 + (g << 2);
    #pragma unroll
    for (int nf = 0; nf < NF; nf++){
      const int n = tn0 + wn*(NF*16) + nf*16 + l15;
      #pragma unroll
      for (int rr = 0; rr < 4; rr++){
        const int m = mb + rr;
        float v = acc[mf][nf][rr];
        if constexpr (EPI == 0){
          ((float*)Cv)[(size_t)kz*((size_t)M*N) + (size_t)m*N + n] = v;
        } else if constexpr (EPI == 1){
          const int sel = n >> 10, nn = n & 1023;
          const int hh = nn >> 6, d = nn & 63;
          if (sel == 0) v *= SC2F;                     // pre-scale Q for exp2-domain softmax
          ((u16*)Cv)[(size_t)sel*((size_t)M_*D_) +
                     ((((size_t)(m >> 11)*H_ + hh)*T_ + (m & 2047)) << 6) + d] = f2b(v);
        } else {
          float u = v + bias[n];
          float t2 = 0.7978845608f*(u + 0.044715f*u*u*u);
          float e = __expf(2.0f*t2);
          float th = 1.0f - 2.0f/(e + 1.0f);
          ((u16*)Cv)[(size_t)m*N + n] = f2b(0.5f*u*(1.0f + th));
        }
      }
    }
  }
}

// ---------- causal flash attention (unchanged from round 5) ----------
__global__ __launch_bounds__(256) void attn_k(const u16* __restrict__ Qg, const u16* __restrict__ Kg,
                                              const u16* __restrict__ Vg, u16* __restrict__ ctx){
  const int flat = blockIdx.x + (blockIdx.y << 4);
  const int xcd = flat & 7, j_ = flat >> 3;
  const int bh  = ((j_ & 3) << 3) + xcd;
  const int pr_ = j_ >> 2;
  const int tid = threadIdx.x;
  const int lane = tid & 63;
  const int w = tid >> 6;
  const int g = lane >> 4, l15 = lane & 15;

  __shared__ __align__(16) u16 Qs[64*64];
  __shared__ __align__(16) u16 Ks[2][64*64];
  __shared__ __align__(16) u16 Vt[2][64*64];
  __shared__ __align__(16) u16 Pl[4][16*64];

  const size_t hb = (size_t)bh * ((size_t)T_*HD_);
  const u16* Qh = Qg + hb;
  const u16* Kh = Kg + hb;
  const u16* Vh = Vg + hb;
  const int b = bh >> 4, hh = bh & 15;

  const int s_r0 = tid >> 3,        s_c0 = (((tid & 7) ^ (s_r0 & 7)) << 3);
  const int s_r1 = (256+tid) >> 3,  s_c1 = ((((256+tid) & 7) ^ (s_r1 & 7)) << 3);
  const int v_kr = tid >> 2, v_d0 = (tid & 3) << 4;

#define SINK_V(buf, q0, q1, q2, q3) do {                                          \
    u16 vv[16] = {q0.x,q0.y,q0.z,q0.w, q1.x,q1.y,q1.z,q1.w,                       \
                  q2.x,q2.y,q2.z,q2.w, q3.x,q3.y,q3.z,q3.w};                      \
    _Pragma("unroll")                                                             \
    for (int j = 0; j < 16; j++){                                                 \
      int d = v_d0 + j;                                                           \
      Vt[buf][d*64 + ((((v_kr >> 3) ^ (d & 7) ^ ((d >> 4) << 1)) & 7) << 3)       \
              + (v_kr & 7)] = vv[j];                                              \
    }                                                                             \
  } while (0)

  for (int ph = 0; ph < 2; ++ph){
    const int qt = ph ? (31 - pr_) : pr_;

    gl_lds16(Qh + (size_t)(qt*64 + s_r0)*HD_ + s_c0, Qs + tid*8);
    gl_lds16(Qh + (size_t)(qt*64 + s_r1)*HD_ + s_c1, Qs + (256+tid)*8);
    gl_lds16(Kh + (size_t)(s_r0)*HD_ + s_c0, Ks[0] + tid*8);
    gl_lds16(Kh + (size_t)(s_r1)*HD_ + s_c1, Ks[0] + (256+tid)*8);
    {
      const u16* vs = Vh + (size_t)v_kr*HD_ + v_d0;
      ushort4 a0 = *(const ushort4*)(vs + 0);
      ushort4 a1 = *(const ushort4*)(vs + 4);
      ushort4 a2 = *(const ushort4*)(vs + 8);
      ushort4 a3 = *(const ushort4*)(vs + 12);
      SINK_V(0, a0, a1, a2, a3);
    }
    __syncthreads();

    s16x8 qa[2];
    #pragma unroll
    for (int kk = 0; kk < 2; kk++){
      int ra = (w << 4) + l15;
      int slot = (kk << 2) + g;
      qa[kk] = *reinterpret_cast<const s16x8*>(Qs + ra*64 + ((slot ^ (ra & 7)) << 3));
    }

    f32x4 accO[4];
    #pragma unroll
    for (int j = 0; j < 4; j++) accO[j] = (f32x4){0.f,0.f,0.f,0.f};
    float mrow = -1e30f, lrow = 0.f;
    const int qlt = (w << 4) + l15;

    for (int kt = 0; kt <= qt; ++kt){
      const int cur = kt & 1, nxt = cur ^ 1;
      const bool pf = (kt < qt);

      ushort4 p0, p1, p2, p3;
      if (pf){
        gl_lds16(Kh + (size_t)((kt+1)*64 + s_r0)*HD_ + s_c0, Ks[nxt] + tid*8);
        gl_lds16(Kh + (size_t)((kt+1)*64 + s_r1)*HD_ + s_c1, Ks[nxt] + (256+tid)*8);
        const u16* vs = Vh + (size_t)((kt+1)*64 + v_kr)*HD_ + v_d0;
        p0 = *(const ushort4*)(vs + 0);
        p1 = *(const ushort4*)(vs + 4);
        p2 = *(const ushort4*)(vs + 8);
        p3 = *(const ushort4*)(vs + 12);
      }

      f32x4 accS[4];
      #pragma unroll
      for (int j = 0; j < 4; j++) accS[j] = (f32x4){0.f,0.f,0.f,0.f};
      __builtin_amdgcn_s_setprio(1);
      #pragma unroll
      for (int jn = 0; jn < 4; jn++){
        #pragma unroll
        for (int kk = 0; kk < 2; kk++){
          int rb = (jn << 4) + l15;
          int slot = (kk << 2) + g;
          s16x8 kf = *reinterpret_cast<const s16x8*>(Ks[cur] + rb*64 + ((slot ^ (rb & 7)) << 3));
          accS[jn] = __builtin_amdgcn_mfma_f32_16x16x32_bf16(kf, qa[kk], accS[jn], 0, 0, 0);
        }
      }
      __builtin_amdgcn_s_setprio(0);

      float sv[4][4];
      #pragma unroll
      for (int jn = 0; jn < 4; jn++)
        #pragma unroll
        for (int rr = 0; rr < 4; rr++){
          float xv = accS[jn][rr];
          if (kt == qt){
            int kl = (jn << 4) + (g << 2) + rr;
            if (kl > qlt) xv = -1e30f;
          }
          sv[jn][rr] = xv;
        }

      float rmax = sv[0][0];
      #pragma unroll
      for (int jn = 0; jn < 4; jn++)
        #pragma unroll
        for (int rr = 0; rr < 4; rr++) rmax = fmaxf(rmax, sv[jn][rr]);
      rmax = fmaxf(rmax, __shfl_xor(rmax, 16));
      rmax = fmaxf(rmax, __shfl_xor(rmax, 32));

      if (__any(rmax > mrow + 8.0f)){
        float mn = fmaxf(mrow, rmax);
        float sf = exp2f(mrow - mn);
        mrow = mn;
        lrow *= sf;
        #pragma unroll
        for (int rr = 0; rr < 4; rr++){
          float sfr = __shfl(sf, ((lane >> 4) << 2) + rr);
          #pragma unroll
          for (int jn = 0; jn < 4; jn++) accO[jn][rr] *= sfr;
        }
      }

      float tsum = 0.f;
      #pragma unroll
      for (int jn = 0; jn < 4; jn++){
        float pv0 = exp2f(sv[jn][0] - mrow);
        float pv1 = exp2f(sv[jn][1] - mrow);
        float pv2 = exp2f(sv[jn][2] - mrow);
        float pv3 = exp2f(sv[jn][3] - mrow);
        tsum += (pv0 + pv1) + (pv2 + pv3);
        int slot = (jn << 1) | (g >> 1);
        int base = l15*64 + (((slot ^ (l15 & 7)) & 7) << 3) + ((g & 1) << 2);
        uint2 pkd = make_uint2(pk2(pv0, pv1), pk2(pv2, pv3));
        *reinterpret_cast<uint2*>(&Pl[w][base]) = pkd;
      }
      tsum += __shfl_xor(tsum, 16);
      tsum += __shfl_xor(tsum, 32);
      lrow += tsum;

      __builtin_amdgcn_s_setprio(1);
      #pragma unroll
      for (int kk = 0; kk < 2; kk++){
        int slot = (kk << 2) + g;
        s16x8 pa = *reinterpret_cast<const s16x8*>(
            &Pl[w][l15*64 + (((slot ^ (l15 & 7)) & 7) << 3)]);
        #pragma unroll
        for (int jn = 0; jn < 4; jn++){
          int vd = (jn << 4) + l15;
          s16x8 vbf = *reinterpret_cast<const s16x8*>(
              Vt[cur] + vd*64 + (((slot ^ (vd & 7) ^ ((vd >> 4) << 1)) & 7) << 3));
          accO[jn] = __builtin_amdgcn_mfma_f32_16x16x32_bf16(pa, vbf, accO[jn], 0, 0, 0);
        }
      }
      __builtin_amdgcn_s_setprio(0);

      if (pf) SINK_V(nxt, p0, p1, p2, p3);
      __syncthreads();
    }

    #pragma unroll
    for (int rr = 0; rr < 4; rr++){
      float lr = __shfl(lrow, ((lane >> 4) << 2) + rr);
      float inv = 1.0f / lr;
      int qrow = qt*64 + (w << 4) + (g << 2) + rr;
      size_t rowbase = ((size_t)(b*T_ + qrow) << 10) + ((size_t)hh << 6);
      #pragma unroll
      for (int jn = 0; jn < 4; jn++){
        int d = (jn << 4) + l15;
        ctx[rowbase + d] = f2b(accO[jn][rr] * inv);
      }
    }
  }
#undef SINK_V
}

// ---------- launch ----------
extern "C" void kernel_launch(void* const* d_in, const int* in_sizes, int n_in,
                              void* d_out, int out_size, void* d_ws, size_t ws_size,
                              hipStream_t stream){
  (void)in_sizes; (void)n_in; (void)out_size; (void)ws_size;
  const float* x    = (const float*)d_in[0];
  const float* wq   = (const float*)d_in[1];
  const float* wk   = (const float*)d_in[2];
  const float* wv   = (const float*)d_in[3];
  const float* wo   = (const float*)d_in[4];
  const float* bo   = (const float*)d_in[5];
  const float* ln1s = (const float*)d_in[6];
  const float* ln1b = (const float*)d_in[7];
  const float* ln2s = (const float*)d_in[8];
  const float* ln2b = (const float*)d_in[9];
  const float* w1   = (const float*)d_in[10];
  const float* b1   = (const float*)d_in[11];
  const float* w2   = (const float*)d_in[12];
  const float* b2   = (const float*)d_in[13];
  float* out = (float*)d_out;

  char* p = (char*)d_ws;
  u16*  wqkvT = (u16*)p;  p += (size_t)3*D_*D_*2;
  u16*  woT   = (u16*)p;  p += (size_t)D_*D_*2;
  u16*  w1T   = (u16*)p;  p += (size_t)D_*DFF_*2;
  u16*  w2T   = (u16*)p;  p += (size_t)DFF_*D_*2;
  u16*  h     = (u16*)p;  p += (size_t)M_*D_*2;
  u16*  qb    = (u16*)p;  p += (size_t)M_*D_*2;
  u16*  kb    = (u16*)p;  p += (size_t)M_*D_*2;
  u16*  vb    = (u16*)p;  p += (size_t)M_*D_*2;
  u16*  ctx   = (u16*)p;  p += (size_t)M_*D_*2;
  float* x1   = (float*)p; p += (size_t)M_*D_*4;
  u16*  h2    = (u16*)p;  p += (size_t)M_*D_*2;
  u16*  ff1   = (u16*)p;  p += (size_t)M_*DFF_*2;
  (void)kb; (void)vb;
  float* part = (float*)h;   // [2][M][1024] fp32 recycled over dead h..vb region

  dim3 blk(256), blk8(512);
  wconv_all<<<3072, blk, 0, stream>>>(wq, wk, wv, wo, w1, w2, wqkvT, woT, w1T, w2T);
  ln_kernel<<<M_, blk, 0, stream>>>(x, ln1s, ln1b, h);
  gemm8<1,4><<<dim3(12,16,1), blk8, 0, stream>>>(h, wqkvT, nullptr, qb, M_, 3*D_, D_, D_);
  attn_k<<<dim3(16,32), blk, 0, stream>>>(qb, qb + (size_t)M_*D_, qb + 2*(size_t)M_*D_, ctx);
  gemm8<0,2><<<dim3(8,16,2), blk8, 0, stream>>>(ctx, woT, nullptr, part, M_, D_, D_/2, D_);
  reduce_ln<<<M_, blk, 0, stream>>>(part, bo, x, ln2s, ln2b, x1, h2);
  gemm8<3,4><<<dim3(16,16,1), blk8, 0, stream>>>(h2, w1T, b1, ff1, M_, DFF_, D_, D_);
  gemm8<0,2><<<dim3(8,16,2), blk8, 0, stream>>>(ff1, w2T, nullptr, part, M_, D_, DFF_/2, DFF_);
  reduce2<<<M_, blk, 0, stream>>>(part, b2, x1, out);
}